// Round 12
// baseline (530.118 us; speedup 1.0000x reference)
//
#include <hip/hip_runtime.h>
#include <hip/hip_bf16.h>
#include <math.h>

#define Bc 8
#define Tc 8192
#define NTOK 256
#define Dc 512
#define TXT 768
#define TEc 2048
#define Hc 8
#define DHc 64
#define MROWS (Bc * Tc)   // 65536

typedef __attribute__((ext_vector_type(8))) short bf16x8v;
typedef __attribute__((ext_vector_type(8))) unsigned short u16x8;
typedef __attribute__((ext_vector_type(4))) unsigned short u16x4;
typedef __attribute__((ext_vector_type(4))) float f32x4;

#define MFMA16(a, b, c) __builtin_amdgcn_mfma_f32_16x16x32_bf16(a, b, c, 0, 0, 0)

__device__ __forceinline__ unsigned short f2bf(float f) {
    __hip_bfloat16 h = __float2bfloat16(f);
    return __builtin_bit_cast(unsigned short, h);
}
__device__ __forceinline__ float bf2f(unsigned short u) {
    unsigned int x = ((unsigned int)u) << 16;
    return __builtin_bit_cast(float, x);
}

typedef __attribute__((address_space(3))) unsigned int lds_u32_t;
typedef __attribute__((address_space(1))) const unsigned int gbl_u32_t;
__device__ __forceinline__ void gload16(const unsigned short* g, short* l) {
    __builtin_amdgcn_global_load_lds((gbl_u32_t*)g, (lds_u32_t*)l, 16, 0, 0);
}

// ---------------------------------------------------------------------------
// prep: 4 weight transposes + ln_t + emb (864 small blocks, one launch).
// ln_x stays standalone (needs zero LDS for full TLP — r11 lesson).
// ---------------------------------------------------------------------------
__device__ __forceinline__ void transpose_tile(const float* __restrict__ src,
                                               unsigned short* __restrict__ dst,
                                               int N, int rs, int k0, int n0,
                                               char* smem) {
    float (*tile)[65] = (float(*)[65])smem;
    int tx = threadIdx.x & 63, tq = threadIdx.x >> 6;
#pragma unroll
    for (int i = 0; i < 16; ++i) {
        int kk = tq + i * 4;
        tile[kk][tx] = src[(size_t)(k0 + kk) * N + n0 + tx];
    }
    __syncthreads();
#pragma unroll
    for (int i = 0; i < 16; ++i) {
        int nn = tq + i * 4;
        dst[(size_t)(n0 + nn) * rs + k0 + tx] = f2bf(tile[tx][nn]);
    }
}

__device__ __forceinline__ void emb_block(int bid, const float* __restrict__ emb,
                                          const float* __restrict__ emb_W,
                                          const float* __restrict__ emb_b,
                                          float* __restrict__ eo, char* smem) {
    float* s   = (float*)smem;                 // [4][2048]
    float* red = (float*)(smem + 32768);       // [4][64][4]
    const int tid = threadIdx.x;
    const int chunk = bid >> 1, bh = bid & 1;
#pragma unroll
    for (int j = 0; j < 8; ++j) {
        int idx = tid + 256 * j;
        int bi = idx >> 9, kk4 = (idx & 511) * 4;
#pragma unroll
        for (int e = 0; e < 4; ++e) {
            float v = emb[(bh * 4 + bi) * TEc + kk4 + e];
            s[bi * TEc + kk4 + e] = v / (1.f + __expf(-v));
        }
    }
    __syncthreads();
    int c = tid & 63, q = tid >> 6;
    int col = chunk * 64 + c;
    float acc[4] = {0.f, 0.f, 0.f, 0.f};
    for (int kk = q * 512; kk < q * 512 + 512; ++kk) {
        float wv = emb_W[(size_t)kk * (2 * Dc) + col];
#pragma unroll
        for (int bi = 0; bi < 4; ++bi) acc[bi] += s[bi * TEc + kk] * wv;
    }
#pragma unroll
    for (int bi = 0; bi < 4; ++bi) red[(q * 64 + c) * 4 + bi] = acc[bi];
    __syncthreads();
    if (q == 0) {
        float bb = emb_b[col];
#pragma unroll
        for (int bi = 0; bi < 4; ++bi)
            eo[(bh * 4 + bi) * (2 * Dc) + col] =
                red[(0 * 64 + c) * 4 + bi] + red[(1 * 64 + c) * 4 + bi] +
                red[(2 * 64 + c) * 4 + bi] + red[(3 * 64 + c) * 4 + bi] + bb;
    }
}

__global__ void __launch_bounds__(256) prep_kernel(
    const float* __restrict__ Wq, const float* __restrict__ oW,
    const float* __restrict__ Wk, const float* __restrict__ Wv,
    const float* __restrict__ xf, const float* __restrict__ ln_t_g,
    const float* __restrict__ ln_t_b,
    unsigned short* __restrict__ Wqt, unsigned short* __restrict__ oWt,
    unsigned short* __restrict__ Wkvt, unsigned short* __restrict__ xt,
    const float* __restrict__ emb, const float* __restrict__ emb_W,
    const float* __restrict__ emb_b, float* __restrict__ eo) {
    __shared__ __align__(16) char smem[36864];
    int bid = blockIdx.x;
    if (bid < 64) {
        transpose_tile(Wq, Wqt, Dc, Dc, (bid >> 3) * 64, (bid & 7) * 64, smem);
        return;
    }
    if (bid < 128) {
        int i = bid - 64;
        transpose_tile(oW, oWt, Dc, Dc, (i >> 3) * 64, (i & 7) * 64, smem);
        return;
    }
    if (bid < 224) {
        int i = bid - 128;
        transpose_tile(Wk, Wkvt, Dc, TXT, (i >> 3) * 64, (i & 7) * 64, smem);
        return;
    }
    if (bid < 320) {
        int i = bid - 224;
        transpose_tile(Wv, Wkvt + (size_t)512 * TXT, Dc, TXT, (i >> 3) * 64, (i & 7) * 64, smem);
        return;
    }
    if (bid < 832) {
        // ln_t: 512 blocks x 4 rows
        int w = threadIdx.x >> 6, l = threadIdx.x & 63;
        int row = (bid - 320) * 4 + w;
        const float* src = xf + (size_t)row * TXT;
        float4 a0 = *(const float4*)&src[l * 12];
        float4 a1 = *(const float4*)&src[l * 12 + 4];
        float4 a2 = *(const float4*)&src[l * 12 + 8];
        float vals[12] = {a0.x, a0.y, a0.z, a0.w, a1.x, a1.y, a1.z, a1.w,
                          a2.x, a2.y, a2.z, a2.w};
        float s = 0.f, ss = 0.f;
#pragma unroll
        for (int j = 0; j < 12; ++j) { s += vals[j]; ss += vals[j] * vals[j]; }
#pragma unroll
        for (int m = 1; m <= 32; m <<= 1) { s += __shfl_xor(s, m); ss += __shfl_xor(ss, m); }
        float mean = s * (1.f / TXT), var = ss * (1.f / TXT) - mean * mean;
        float rs = rsqrtf(var + 1e-5f);
        unsigned short o[12];
#pragma unroll
        for (int j = 0; j < 12; ++j) {
            int c = l * 12 + j;
            o[j] = f2bf((vals[j] - mean) * rs * ln_t_g[c] + ln_t_b[c]);
        }
        unsigned short* dp = xt + (size_t)row * TXT + l * 12;
        *(u16x4*)&dp[0] = *(u16x4*)&o[0];
        *(u16x4*)&dp[4] = *(u16x4*)&o[4];
        *(u16x4*)&dp[8] = *(u16x4*)&o[8];
        return;
    }
    emb_block(bid - 832, emb, emb_W, emb_b, eo, smem);
}

// ---------------------------------------------------------------------------
// ln_x: A1 = bf16(LN(x)), one wave per row (r5-proven; zero LDS)
// ---------------------------------------------------------------------------
__global__ void __launch_bounds__(256) ln_x_kernel(const float* __restrict__ x,
                                                   const float* __restrict__ g,
                                                   const float* __restrict__ bt,
                                                   unsigned short* __restrict__ A1) {
    int w = threadIdx.x >> 6, l = threadIdx.x & 63;
    int row = blockIdx.x * 4 + w;
    const float* src = x + (size_t)row * Dc;
    float4 a0 = *(const float4*)&src[l * 8];
    float4 a1 = *(const float4*)&src[l * 8 + 4];
    float vals[8] = {a0.x, a0.y, a0.z, a0.w, a1.x, a1.y, a1.z, a1.w};
    float s = 0.f, ss = 0.f;
#pragma unroll
    for (int j = 0; j < 8; ++j) { s += vals[j]; ss += vals[j] * vals[j]; }
#pragma unroll
    for (int m = 1; m <= 32; m <<= 1) { s += __shfl_xor(s, m); ss += __shfl_xor(ss, m); }
    float mean = s * (1.f / Dc), var = ss * (1.f / Dc) - mean * mean;
    float rs = rsqrtf(var + 1e-5f);
    u16x8 o;
#pragma unroll
    for (int j = 0; j < 8; ++j) {
        int c = l * 8 + j;
        o[j] = f2bf((vals[j] - mean) * rs * g[c] + bt[c]);
    }
    *(u16x8*)&A1[(size_t)row * Dc + l * 8] = o;
}

// ---------------------------------------------------------------------------
// kvgemm: [2048x768] @ [768x1024] -> k (softmaxed) | v  (r3-proven)
// ---------------------------------------------------------------------------
__global__ void __launch_bounds__(256) kvgemm_kernel(
    const unsigned short* __restrict__ xt, const unsigned short* __restrict__ Wkvt,
    const float* __restrict__ bk, const float* __restrict__ bv,
    unsigned short* __restrict__ kbuf, unsigned short* __restrict__ vbuf) {
    __shared__ short lds_s[16384];
    short* Alds = lds_s;
    short* Blds = lds_s + 8192;

    const int tid = threadIdx.x, l = tid & 63, w = tid >> 6;
    const int lr = l & 15, lg = l >> 4;
    int mt = blockIdx.x >> 3, nt = blockIdx.x & 7;
    int row0 = mt * 128, col0 = nt * 128;
    int wrow = (w >> 1) * 64, wcol = (w & 1) * 64;

    f32x4 acc[4][4] = {};
    const int cbase = w * 64 + l;

    for (int ks = 0; ks < 12; ++ks) {
#pragma unroll
        for (int i = 0; i < 4; ++i) {
            int c = i * 256 + cbase;
            int r = c >> 3, kc = c & 7;
            int koff = ks * 64 + ((kc ^ (r & 7)) << 3);
            gload16(xt + (size_t)(row0 + r) * TXT + koff, &Alds[((i * 4 + w) * 64) * 8]);
            gload16(Wkvt + (size_t)(col0 + r) * TXT + koff, &Blds[((i * 4 + w) * 64) * 8]);
        }
        __syncthreads();
#pragma unroll
        for (int kk = 0; kk < 2; ++kk) {
            int kcw = kk * 4 + lg;
            bf16x8v af[4], bfr[4];
#pragma unroll
            for (int i = 0; i < 4; ++i) {
                int r = wrow + i * 16 + lr;
                af[i] = *(bf16x8v*)&Alds[(r * 8 + (kcw ^ (r & 7))) * 8];
            }
#pragma unroll
            for (int j = 0; j < 4; ++j) {
                int n = wcol + j * 16 + lr;
                bfr[j] = *(bf16x8v*)&Blds[(n * 8 + (kcw ^ (n & 7))) * 8];
            }
#pragma unroll
            for (int i = 0; i < 4; ++i)
#pragma unroll
                for (int j = 0; j < 4; ++j)
                    acc[i][j] = MFMA16(af[i], bfr[j], acc[i][j]);
        }
        __syncthreads();
    }

    const bool kHalf = (col0 + wcol) < 512;
    int cj[4];
    float bias[4];
#pragma unroll
    for (int j = 0; j < 4; ++j) {
        cj[j] = col0 + wcol + j * 16 + lr;
        bias[j] = kHalf ? bk[cj[j]] : bv[cj[j] - 512];
    }
#pragma unroll
    for (int i = 0; i < 4; ++i)
#pragma unroll
        for (int reg = 0; reg < 4; ++reg) {
            float v0 = acc[i][0][reg] + bias[0], v1 = acc[i][1][reg] + bias[1];
            float v2 = acc[i][2][reg] + bias[2], v3 = acc[i][3][reg] + bias[3];
            if (kHalf) {
                float m = fmaxf(fmaxf(v0, v1), fmaxf(v2, v3));
                m = fmaxf(m, __shfl_xor(m, 1)); m = fmaxf(m, __shfl_xor(m, 2));
                m = fmaxf(m, __shfl_xor(m, 4)); m = fmaxf(m, __shfl_xor(m, 8));
                float e0 = __expf(v0 - m), e1 = __expf(v1 - m);
                float e2 = __expf(v2 - m), e3 = __expf(v3 - m);
                float ssum = e0 + e1 + e2 + e3;
                ssum += __shfl_xor(ssum, 1); ssum += __shfl_xor(ssum, 2);
                ssum += __shfl_xor(ssum, 4); ssum += __shfl_xor(ssum, 8);
                float inv = 1.f / ssum;
                v0 = e0 * inv; v1 = e1 * inv; v2 = e2 * inv; v3 = e3 * inv;
            }
            int r = row0 + wrow + i * 16 + 4 * lg + reg;
            float vv[4] = {v0, v1, v2, v3};
#pragma unroll
            for (int j = 0; j < 4; ++j) {
                if (kHalf) kbuf[(size_t)r * Dc + cj[j]] = f2bf(vv[j]);
                else       vbuf[(size_t)r * Dc + cj[j] - 512] = f2bf(vv[j]);
            }
        }
}

// ---------------------------------------------------------------------------
// attn: attn_t[b,h][l][d] = sum_n k[b,n,h,d]*v[b,n,h,l]
// ---------------------------------------------------------------------------
__global__ void __launch_bounds__(512) attn_kernel(const unsigned short* __restrict__ kbuf,
                                                   const unsigned short* __restrict__ vbuf,
                                                   unsigned short* __restrict__ attn_t) {
    __shared__ unsigned short ksh[128][DHc], vsh[128][DHc];
    const int tid = threadIdx.x;
    const int b = blockIdx.x >> 3, h = blockIdx.x & 7;
    const int d = tid >> 3, lb = (tid & 7) * 8;
    const int tok = tid >> 2, c0 = (tid & 3) * 16;
    float acc[8] = {0.f};
    for (int st = 0; st < 2; ++st) {
        __syncthreads();
        size_t o = (size_t)(b * NTOK + st * 128 + tok) * Dc + h * DHc + c0;
        *(u16x8*)&ksh[tok][c0]     = *(const u16x8*)&kbuf[o];
        *(u16x8*)&ksh[tok][c0 + 8] = *(const u16x8*)&kbuf[o + 8];
        *(u16x8*)&vsh[tok][c0]     = *(const u16x8*)&vbuf[o];
        *(u16x8*)&vsh[tok][c0 + 8] = *(const u16x8*)&vbuf[o + 8];
        __syncthreads();
        for (int n = 0; n < 128; ++n) {
            float kd = bf2f(ksh[n][d]);
            u16x4 va = *(const u16x4*)&vsh[n][lb];
            u16x4 vb = *(const u16x4*)&vsh[n][lb + 4];
#pragma unroll
            for (int e = 0; e < 4; ++e) acc[e] += kd * bf2f(va[e]);
#pragma unroll
            for (int e = 0; e < 4; ++e) acc[4 + e] += kd * bf2f(vb[e]);
        }
    }
    size_t base = (size_t)(b * 8 + h) * DHc * DHc;
#pragma unroll
    for (int e = 0; e < 8; ++e)
        attn_t[base + (size_t)(lb + e) * DHc + d] = f2bf(acc[e]);
}

// ---------------------------------------------------------------------------
// gemm1: BM=256, BN=128, BK=64, 512 thr (r5-proven) + row-stats epilogue.
// A1 @ Wqt + bq -> head-softmax -> q @ attn_t -> out1 bf16; stats[cb][row][2]
// ---------------------------------------------------------------------------
__global__ void __launch_bounds__(512, 4) gemm1_kernel(
    const unsigned short* __restrict__ A1, const unsigned short* __restrict__ Wt,
    const float* __restrict__ bq, const unsigned short* __restrict__ attn_t,
    unsigned short* __restrict__ out1, float* __restrict__ stats) {
    __shared__ short lds_s[24576];            // 48 KB: A [0:16384), B [16384:24576)
    short* Alds = lds_s;
    short* Blds = lds_s + 16384;

    const int tid = threadIdx.x, l = tid & 63, w = tid >> 6;
    const int lr = l & 15, lg = l >> 4;
    int raw = blockIdx.x;                      // 1024 blocks, %8==0 -> bijective
    int swz = (raw & 7) * 128 + (raw >> 3);
    int mt = swz >> 2, nt = swz & 3;
    int row0 = mt * 256, col0 = nt * 128;
    int b = row0 >> 13;
    int wrow = (w >> 1) * 64, wcol = (w & 1) * 64;

    f32x4 acc[4][4] = {};

    for (int ks = 0; ks < 8; ++ks) {
#pragma unroll
        for (int i = 0; i < 4; ++i) {          // A: 256 rows x 64 k
            int c = i * 512 + tid;
            int r = c >> 3, kc = c & 7;
            int koff = ks * 64 + ((kc ^ (r & 7)) << 3);
            gload16(A1 + (size_t)(row0 + r) * Dc + koff, &Alds[(i * 8 + w) * 512]);
        }
#pragma unroll
        for (int i = 0; i < 2; ++i) {          // B: 128 rows x 64 k
            int c = i * 512 + tid;
            int r = c >> 3, kc = c & 7;
            int koff = ks * 64 + ((kc ^ (r & 7)) << 3);
            gload16(Wt + (size_t)(col0 + r) * Dc + koff, &Blds[(i * 8 + w) * 512]);
        }
        __syncthreads();
#pragma unroll
        for (int kk = 0; kk < 2; ++kk) {
            int kcw = kk * 4 + lg;
            bf16x8v af[4], bfr[4];
#pragma unroll
            for (int i = 0; i < 4; ++i) {
                int r = wrow + i * 16 + lr;
                af[i] = *(bf16x8v*)&Alds[(r * 8 + (kcw ^ (r & 7))) * 8];
            }
#pragma unroll
            for (int j = 0; j < 4; ++j) {
                int n = wcol + j * 16 + lr;
                bfr[j] = *(bf16x8v*)&Blds[(n * 8 + (kcw ^ (n & 7))) * 8];
            }
#pragma unroll
            for (int i = 0; i < 4; ++i)
#pragma unroll
                for (int j = 0; j < 4; ++j)
                    acc[i][j] = MFMA16(af[i], bfr[j], acc[i][j]);
        }
        __syncthreads();
    }

    float bqv[4];
#pragma unroll
    for (int j = 0; j < 4; ++j) bqv[j] = bq[col0 + wcol + j * 16 + lr];

    // PV B-frags: wave's 64-col block == one head
    int hw = nt * 2 + (wcol >> 6);
    const int cb = nt * 2 + (wcol >> 6);       // stats col-block (same index)
    const unsigned short* at = attn_t + (size_t)(b * 8 + hw) * DHc * DHc;
    short* Qw = lds_s + w * 1024;              // per-wave 16x64 scratch in A region

#pragma unroll
    for (int i = 0; i < 4; ++i) {
        // bias + per-(row,head) softmax (16-lane groups)
#pragma unroll
        for (int reg = 0; reg < 4; ++reg) {
            float v0 = acc[i][0][reg] + bqv[0], v1 = acc[i][1][reg] + bqv[1];
            float v2 = acc[i][2][reg] + bqv[2], v3 = acc[i][3][reg] + bqv[3];
            float m = fmaxf(fmaxf(v0, v1), fmaxf(v2, v3));
            m = fmaxf(m, __shfl_xor(m, 1)); m = fmaxf(m, __shfl_xor(m, 2));
            m = fmaxf(m, __shfl_xor(m, 4)); m = fmaxf(m, __shfl_xor(m, 8));
            float e0 = __expf(v0 - m), e1 = __expf(v1 - m);
            float e2 = __expf(v2 - m), e3 = __expf(v3 - m);
            float ssum = e0 + e1 + e2 + e3;
            ssum += __shfl_xor(ssum, 1); ssum += __shfl_xor(ssum, 2);
            ssum += __shfl_xor(ssum, 4); ssum += __shfl_xor(ssum, 8);
            float inv = 1.f / ssum;
            acc[i][0][reg] = e0 * inv; acc[i][1][reg] = e1 * inv;
            acc[i][2][reg] = e2 * inv; acc[i][3][reg] = e3 * inv;
        }
        // q-frag -> per-wave LDS scratch (swizzled), wave-local
#pragma unroll
        for (int j = 0; j < 4; ++j)
#pragma unroll
            for (int reg = 0; reg < 4; ++reg) {
                int rl = 4 * lg + reg;
                int c = j * 16 + lr;
                Qw[(rl * 8 + ((c >> 3) ^ (rl & 7))) * 8 + (c & 7)] =
                    (short)f2bf(acc[i][j][reg]);
            }
        // PV: 16 rows of this frag x attn (64x64)
        f32x4 acc2[4] = {};
#pragma unroll
        for (int kk = 0; kk < 2; ++kk) {
            int kc = kk * 4 + lg;
            bf16x8v a = *(bf16x8v*)&Qw[(lr * 8 + (kc ^ (lr & 7))) * 8];
            bf16x8v bf2[4];
#pragma unroll
            for (int j = 0; j < 4; ++j)
                bf2[j] = *(const bf16x8v*)&at[(j * 16 + lr) * DHc + kk * 32 + lg * 8];
#pragma unroll
            for (int j = 0; j < 4; ++j)
                acc2[j] = MFMA16(a, bf2[j], acc2[j]);
        }
        // row stats over this wave's 64 cols (sum, sumsq) for fused LN in gemm2m
#pragma unroll
        for (int reg = 0; reg < 4; ++reg) {
            float s  = acc2[0][reg] + acc2[1][reg] + acc2[2][reg] + acc2[3][reg];
            float ss = acc2[0][reg] * acc2[0][reg] + acc2[1][reg] * acc2[1][reg]
                     + acc2[2][reg] * acc2[2][reg] + acc2[3][reg] * acc2[3][reg];
            s += __shfl_xor(s, 1); ss += __shfl_xor(ss, 1);
            s += __shfl_xor(s, 2); ss += __shfl_xor(ss, 2);
            s += __shfl_xor(s, 4); ss += __shfl_xor(ss, 4);
            s += __shfl_xor(s, 8); ss += __shfl_xor(ss, 8);
            if (lr == 0) {
                int r = row0 + wrow + i * 16 + 4 * lg + reg;
                *(float2*)&stats[((size_t)cb * MROWS + r) * 2] = make_float2(s, ss);
            }
        }
#pragma unroll
        for (int j = 0; j < 4; ++j)
#pragma unroll
            for (int reg = 0; reg < 4; ++reg) {
                int r = row0 + wrow + i * 16 + 4 * lg + reg;
                int c = col0 + wcol + j * 16 + lr;
                out1[(size_t)r * Dc + c] = f2bf(acc2[j][reg]);
            }
    }
}

// ---------------------------------------------------------------------------
// gemm2m: fused mid + GEMM2. BM=256, BN=128, BK=64, 512 thr.
// A-staging: out1 -> reg -> LN(stats)+FiLM+SiLU -> bf16 -> swizzled ds_write.
// B via gload16. out = x + A @ oWt + out_b (fp32).
// ---------------------------------------------------------------------------
__global__ void __launch_bounds__(512, 3) gemm2m_kernel(
    const unsigned short* __restrict__ out1, const float* __restrict__ stats,
    const float* __restrict__ lng, const float* __restrict__ lnb,
    const float* __restrict__ eo, const unsigned short* __restrict__ Wt,
    const float* __restrict__ ob, const float* __restrict__ x,
    float* __restrict__ out) {
    __shared__ short lds_s[24576];            // A 32KB | B 16KB
    __shared__ float Gp[Dc], Bp[Dc];          // fused params (4KB)
    short* Alds = lds_s;
    short* Blds = lds_s + 16384;

    const int tid = threadIdx.x, l = tid & 63, w = tid >> 6;
    const int lr = l & 15, lg = l >> 4;
    int raw = blockIdx.x;
    int swz = (raw & 7) * 128 + (raw >> 3);
    int mt = swz >> 2, nt = swz & 3;
    int row0 = mt * 256, col0 = nt * 128;
    int b = row0 >> 13;
    int wrow = (w >> 1) * 64, wcol = (w & 1) * 64;

    // ---- fused-transform params: Gp = g*(1+scale), Bp = b*(1+scale)+shift
    {
        const float* scl = eo + (size_t)b * (2 * Dc);
        const float* shf = scl + Dc;
        float sc = scl[tid], sh = shf[tid];
        Gp[tid] = lng[tid] * (1.f + sc);
        Bp[tid] = lnb[tid] * (1.f + sc) + sh;
    }
    // ---- per-thread staging rows: r = i*64 + (tid>>3); combine 8 stat partials
    const int rl_base = tid >> 3, kc = tid & 7;
    float mean[4], rstd[4];
#pragma unroll
    for (int i = 0; i < 4; ++i) {
        int rg = row0 + i * 64 + rl_base;
        float s = 0.f, ss = 0.f;
#pragma unroll
        for (int cbi = 0; cbi < 8; ++cbi) {
            float2 p = *(const float2*)&stats[((size_t)cbi * MROWS + rg) * 2];
            s += p.x; ss += p.y;
        }
        float mn = s * (1.f / Dc);
        mean[i] = mn;
        rstd[i] = rsqrtf(ss * (1.f / Dc) - mn * mn + 1e-5f);
    }
    __syncthreads();   // Gp/Bp ready

    f32x4 acc[4][4] = {};

    for (int ks = 0; ks < 8; ++ks) {
        int c0 = ks * 64 + kc * 8;
        float4 g0 = *(const float4*)&Gp[c0], g1 = *(const float4*)&Gp[c0 + 4];
        float4 b0 = *(const float4*)&Bp[c0], b1 = *(const float4*)&Bp[c0 + 4];
        float gg[8] = {g0.x, g0.y, g0.z, g0.w, g1.x, g1.y, g1.z, g1.w};
        float bb[8] = {b0.x, b0.y, b0.z, b0.w, b1.x, b1.y, b1.z, b1.w};
#pragma unroll
        for (int i = 0; i < 4; ++i) {          // A: reg-stage + transform
            int rl = i * 64 + rl_base;
            u16x8 v = *(const u16x8*)&out1[(size_t)(row0 + rl) * Dc + c0];
            float a = rstd[i], mn = mean[i];
            bf16x8v o;
#pragma unroll
            for (int j = 0; j < 8; ++j) {
                float t = (bf2f(v[j]) - mn) * a;
                t = t * gg[j] + bb[j];
                o[j] = (short)f2bf(t / (1.f + __expf(-t)));
            }
            *(bf16x8v*)&Alds[(rl * 8 + (kc ^ (rl & 7))) * 8] = o;
        }
#pragma unroll
        for (int i = 0; i < 2; ++i) {          // B: 128 rows x 64 k
            int c = i * 512 + tid;
            int r = c >> 3, kcb = c & 7;
            int koff = ks * 64 + ((kcb ^ (r & 7)) << 3);
            gload16(Wt + (size_t)(col0 + r) * Dc + koff, &Blds[(i * 8 + w) * 512]);
        }
        __syncthreads();
#pragma unroll
        for (int kk = 0; kk < 2; ++kk) {
            int kcw = kk * 4 + lg;
            bf16x8v af[4], bfr[4];
#pragma unroll
            for (int i = 0; i < 4; ++i) {
                int r = wrow + i * 16 + lr;
                af[i] = *(bf16x8v*)&Alds[(r * 8 + (kcw ^ (r & 7))) * 8];
            }
#pragma unroll
            for (int j = 0; j < 4; ++j) {
                int n = wcol + j * 16 + lr;
                bfr[j] = *(bf16x8v*)&Blds[(n * 8 + (kcw ^ (n & 7))) * 8];
            }
#pragma unroll
            for (int i = 0; i < 4; ++i)
#pragma unroll
                for (int j = 0; j < 4; ++j)
                    acc[i][j] = MFMA16(af[i], bfr[j], acc[i][j]);
        }
        __syncthreads();
    }

    float obv[4];
#pragma unroll
    for (int j = 0; j < 4; ++j) obv[j] = ob[col0 + wcol + j * 16 + lr];
#pragma unroll
    for (int i = 0; i < 4; ++i)
#pragma unroll
        for (int j = 0; j < 4; ++j)
#pragma unroll
            for (int reg = 0; reg < 4; ++reg) {
                int r = row0 + wrow + i * 16 + 4 * lg + reg;
                int c = col0 + wcol + j * 16 + lr;
                size_t o = (size_t)r * Dc + c;
                out[o] = acc[i][j][reg] + obv[j] + x[o];
            }
}

// ---------------------------------------------------------------------------
extern "C" void kernel_launch(void* const* d_in, const int* in_sizes, int n_in,
                              void* d_out, int out_size, void* d_ws, size_t ws_size,
                              hipStream_t stream) {
    const float* x      = (const float*)d_in[0];
    const float* xf     = (const float*)d_in[1];
    const float* emb    = (const float*)d_in[2];
    const float* ln_x_g = (const float*)d_in[3];
    const float* ln_x_b = (const float*)d_in[4];
    const float* ln_t_g = (const float*)d_in[5];
    const float* ln_t_b = (const float*)d_in[6];
    const float* Wq     = (const float*)d_in[7];
    const float* bq     = (const float*)d_in[8];
    const float* Wk     = (const float*)d_in[9];
    const float* bk     = (const float*)d_in[10];
    const float* Wv     = (const float*)d_in[11];
    const float* bv     = (const float*)d_in[12];
    const float* emb_W  = (const float*)d_in[13];
    const float* emb_b  = (const float*)d_in[14];
    const float* ln_o_g = (const float*)d_in[15];
    const float* ln_o_b = (const float*)d_in[16];
    const float* out_W  = (const float*)d_in[17];
    const float* out_b  = (const float*)d_in[18];
    float* out = (float*)d_out;

    // ws layout (u16 units unless noted)
    unsigned short* xt   = (unsigned short*)d_ws;                 // 2048*768
    unsigned short* kbuf = xt + (size_t)2048 * TXT;               // 2048*512
    unsigned short* vbuf = kbuf + (size_t)2048 * 512;             // 2048*512
    unsigned short* Wkvt = vbuf + (size_t)2048 * 512;             // 1024*768
    unsigned short* Wqt  = Wkvt + (size_t)1024 * TXT;             // 512*512
    unsigned short* oWt  = Wqt + (size_t)512 * 512;               // 512*512
    unsigned short* attn_t = oWt + (size_t)512 * 512;             // 64*64*64
    float* eo = (float*)(attn_t + (size_t)64 * 64 * 64);          // 8*1024 f32
    unsigned short* out1 = (unsigned short*)(eo + 8 * 1024);      // 65536*512
    unsigned short* A1   = out1 + (size_t)MROWS * Dc;             // 65536*512
    float* stats = (float*)(A1 + (size_t)MROWS * Dc);             // 8*65536*2 f32

    hipLaunchKernelGGL(prep_kernel, dim3(864), dim3(256), 0, stream,
                       Wq, out_W, Wk, Wv, xf, ln_t_g, ln_t_b, Wqt, oWt, Wkvt, xt,
                       emb, emb_W, emb_b, eo);
    hipLaunchKernelGGL(ln_x_kernel, dim3(MROWS / 4), dim3(256), 0, stream,
                       x, ln_x_g, ln_x_b, A1);
    hipLaunchKernelGGL(kvgemm_kernel, dim3(16 * 8), dim3(256), 0, stream,
                       xt, Wkvt, bk, bv, kbuf, vbuf);
    hipLaunchKernelGGL(attn_kernel, dim3(Bc * Hc), dim3(512), 0, stream,
                       kbuf, vbuf, attn_t);
    hipLaunchKernelGGL(gemm1_kernel, dim3(MROWS / 256 * 4), dim3(512), 0, stream,
                       A1, Wqt, bq, attn_t, out1, stats);
    hipLaunchKernelGGL(gemm2m_kernel, dim3(MROWS / 256 * 4), dim3(512), 0, stream,
                       out1, stats, ln_o_g, ln_o_b, eo, oWt, out_b, x, out);
}

// Round 13
// 360.016 us; speedup vs baseline: 1.4725x; 1.4725x over previous
//
#include <hip/hip_runtime.h>
#include <hip/hip_bf16.h>
#include <math.h>

#define Bc 8
#define Tc 8192
#define NTOK 256
#define Dc 512
#define TXT 768
#define TEc 2048
#define Hc 8
#define DHc 64
#define MROWS (Bc * Tc)   // 65536

typedef __attribute__((ext_vector_type(8))) short bf16x8v;
typedef __attribute__((ext_vector_type(8))) unsigned short u16x8;
typedef __attribute__((ext_vector_type(4))) unsigned short u16x4;
typedef __attribute__((ext_vector_type(4))) float f32x4;

#define MFMA16(a, b, c) __builtin_amdgcn_mfma_f32_16x16x32_bf16(a, b, c, 0, 0, 0)

__device__ __forceinline__ unsigned short f2bf(float f) {
    __hip_bfloat16 h = __float2bfloat16(f);
    return __builtin_bit_cast(unsigned short, h);
}
__device__ __forceinline__ float bf2f(unsigned short u) {
    unsigned int x = ((unsigned int)u) << 16;
    return __builtin_bit_cast(float, x);
}

typedef __attribute__((address_space(3))) unsigned int lds_u32_t;
typedef __attribute__((address_space(1))) const unsigned int gbl_u32_t;
__device__ __forceinline__ void gload16(const unsigned short* g, short* l) {
    __builtin_amdgcn_global_load_lds((gbl_u32_t*)g, (lds_u32_t*)l, 16, 0, 0);
}

// ---------------------------------------------------------------------------
// prep: 4 weight transposes + ln_t ONLY (832 blocks — r9-proven form).
// emb is standalone again (r12 lesson: a 32-block latency-bound tail inside a
// heterogeneous switch-kernel runs near-serial, +170 us).
// ---------------------------------------------------------------------------
__device__ __forceinline__ void transpose_tile(const float* __restrict__ src,
                                               unsigned short* __restrict__ dst,
                                               int N, int rs, int k0, int n0,
                                               char* smem) {
    float (*tile)[65] = (float(*)[65])smem;
    int tx = threadIdx.x & 63, tq = threadIdx.x >> 6;
#pragma unroll
    for (int i = 0; i < 16; ++i) {
        int kk = tq + i * 4;
        tile[kk][tx] = src[(size_t)(k0 + kk) * N + n0 + tx];
    }
    __syncthreads();
#pragma unroll
    for (int i = 0; i < 16; ++i) {
        int nn = tq + i * 4;
        dst[(size_t)(n0 + nn) * rs + k0 + tx] = f2bf(tile[tx][nn]);
    }
}

__global__ void __launch_bounds__(256) prep_kernel(
    const float* __restrict__ Wq, const float* __restrict__ oW,
    const float* __restrict__ Wk, const float* __restrict__ Wv,
    const float* __restrict__ xf, const float* __restrict__ ln_t_g,
    const float* __restrict__ ln_t_b,
    unsigned short* __restrict__ Wqt, unsigned short* __restrict__ oWt,
    unsigned short* __restrict__ Wkvt, unsigned short* __restrict__ xt) {
    __shared__ __align__(16) char smem[16704];   // 64*65*4 for transpose tile
    int bid = blockIdx.x;
    if (bid < 64) {
        transpose_tile(Wq, Wqt, Dc, Dc, (bid >> 3) * 64, (bid & 7) * 64, smem);
        return;
    }
    if (bid < 128) {
        int i = bid - 64;
        transpose_tile(oW, oWt, Dc, Dc, (i >> 3) * 64, (i & 7) * 64, smem);
        return;
    }
    if (bid < 224) {
        int i = bid - 128;
        transpose_tile(Wk, Wkvt, Dc, TXT, (i >> 3) * 64, (i & 7) * 64, smem);
        return;
    }
    if (bid < 320) {
        int i = bid - 224;
        transpose_tile(Wv, Wkvt + (size_t)512 * TXT, Dc, TXT, (i >> 3) * 64, (i & 7) * 64, smem);
        return;
    }
    // ln_t: 512 blocks x 4 rows
    int w = threadIdx.x >> 6, l = threadIdx.x & 63;
    int row = (bid - 320) * 4 + w;
    const float* src = xf + (size_t)row * TXT;
    float4 a0 = *(const float4*)&src[l * 12];
    float4 a1 = *(const float4*)&src[l * 12 + 4];
    float4 a2 = *(const float4*)&src[l * 12 + 8];
    float vals[12] = {a0.x, a0.y, a0.z, a0.w, a1.x, a1.y, a1.z, a1.w,
                      a2.x, a2.y, a2.z, a2.w};
    float s = 0.f, ss = 0.f;
#pragma unroll
    for (int j = 0; j < 12; ++j) { s += vals[j]; ss += vals[j] * vals[j]; }
#pragma unroll
    for (int m = 1; m <= 32; m <<= 1) { s += __shfl_xor(s, m); ss += __shfl_xor(ss, m); }
    float mean = s * (1.f / TXT), var = ss * (1.f / TXT) - mean * mean;
    float rs = rsqrtf(var + 1e-5f);
    unsigned short o[12];
#pragma unroll
    for (int j = 0; j < 12; ++j) {
        int c = l * 12 + j;
        o[j] = f2bf((vals[j] - mean) * rs * ln_t_g[c] + ln_t_b[c]);
    }
    unsigned short* dp = xt + (size_t)row * TXT + l * 12;
    *(u16x4*)&dp[0] = *(u16x4*)&o[0];
    *(u16x4*)&dp[4] = *(u16x4*)&o[4];
    *(u16x4*)&dp[8] = *(u16x4*)&o[8];
}

// ---------------------------------------------------------------------------
// emb (standalone, r3-proven 128-block k-split form):
// eo[b,:] = silu(emb[b]) @ emb_W + emb_b
// ---------------------------------------------------------------------------
__global__ void __launch_bounds__(256) emb_kernel(const float* __restrict__ emb,
                                                  const float* __restrict__ emb_W,
                                                  const float* __restrict__ emb_b,
                                                  float* __restrict__ eo) {
    __shared__ float s[TEc];
    __shared__ float red[4][64];
    const int tid = threadIdx.x;
    const int b = blockIdx.x >> 4, chunk = blockIdx.x & 15;
#pragma unroll
    for (int j = 0; j < 8; ++j) {
        int idx = tid + 256 * j;
        float e = emb[b * TEc + idx];
        s[idx] = e / (1.f + __expf(-e));
    }
    __syncthreads();
    int c = tid & 63, q = tid >> 6;
    int col = chunk * 64 + c;
    float acc = 0.f;
    for (int kk = q * 512; kk < q * 512 + 512; ++kk)
        acc += s[kk] * emb_W[(size_t)kk * (2 * Dc) + col];
    red[q][c] = acc;
    __syncthreads();
    if (q == 0)
        eo[b * (2 * Dc) + col] = red[0][c] + red[1][c] + red[2][c] + red[3][c] + emb_b[col];
}

// ---------------------------------------------------------------------------
// ln_x: A1 = bf16(LN(x)), one wave per row (r5-proven; zero LDS)
// ---------------------------------------------------------------------------
__global__ void __launch_bounds__(256) ln_x_kernel(const float* __restrict__ x,
                                                   const float* __restrict__ g,
                                                   const float* __restrict__ bt,
                                                   unsigned short* __restrict__ A1) {
    int w = threadIdx.x >> 6, l = threadIdx.x & 63;
    int row = blockIdx.x * 4 + w;
    const float* src = x + (size_t)row * Dc;
    float4 a0 = *(const float4*)&src[l * 8];
    float4 a1 = *(const float4*)&src[l * 8 + 4];
    float vals[8] = {a0.x, a0.y, a0.z, a0.w, a1.x, a1.y, a1.z, a1.w};
    float s = 0.f, ss = 0.f;
#pragma unroll
    for (int j = 0; j < 8; ++j) { s += vals[j]; ss += vals[j] * vals[j]; }
#pragma unroll
    for (int m = 1; m <= 32; m <<= 1) { s += __shfl_xor(s, m); ss += __shfl_xor(ss, m); }
    float mean = s * (1.f / Dc), var = ss * (1.f / Dc) - mean * mean;
    float rs = rsqrtf(var + 1e-5f);
    u16x8 o;
#pragma unroll
    for (int j = 0; j < 8; ++j) {
        int c = l * 8 + j;
        o[j] = f2bf((vals[j] - mean) * rs * g[c] + bt[c]);
    }
    *(u16x8*)&A1[(size_t)row * Dc + l * 8] = o;
}

// ---------------------------------------------------------------------------
// kvgemm: [2048x768] @ [768x1024] -> k (softmaxed) | v  (r3-proven)
// ---------------------------------------------------------------------------
__global__ void __launch_bounds__(256) kvgemm_kernel(
    const unsigned short* __restrict__ xt, const unsigned short* __restrict__ Wkvt,
    const float* __restrict__ bk, const float* __restrict__ bv,
    unsigned short* __restrict__ kbuf, unsigned short* __restrict__ vbuf) {
    __shared__ short lds_s[16384];
    short* Alds = lds_s;
    short* Blds = lds_s + 8192;

    const int tid = threadIdx.x, l = tid & 63, w = tid >> 6;
    const int lr = l & 15, lg = l >> 4;
    int mt = blockIdx.x >> 3, nt = blockIdx.x & 7;
    int row0 = mt * 128, col0 = nt * 128;
    int wrow = (w >> 1) * 64, wcol = (w & 1) * 64;

    f32x4 acc[4][4] = {};
    const int cbase = w * 64 + l;

    for (int ks = 0; ks < 12; ++ks) {
#pragma unroll
        for (int i = 0; i < 4; ++i) {
            int c = i * 256 + cbase;
            int r = c >> 3, kc = c & 7;
            int koff = ks * 64 + ((kc ^ (r & 7)) << 3);
            gload16(xt + (size_t)(row0 + r) * TXT + koff, &Alds[((i * 4 + w) * 64) * 8]);
            gload16(Wkvt + (size_t)(col0 + r) * TXT + koff, &Blds[((i * 4 + w) * 64) * 8]);
        }
        __syncthreads();
#pragma unroll
        for (int kk = 0; kk < 2; ++kk) {
            int kcw = kk * 4 + lg;
            bf16x8v af[4], bfr[4];
#pragma unroll
            for (int i = 0; i < 4; ++i) {
                int r = wrow + i * 16 + lr;
                af[i] = *(bf16x8v*)&Alds[(r * 8 + (kcw ^ (r & 7))) * 8];
            }
#pragma unroll
            for (int j = 0; j < 4; ++j) {
                int n = wcol + j * 16 + lr;
                bfr[j] = *(bf16x8v*)&Blds[(n * 8 + (kcw ^ (n & 7))) * 8];
            }
#pragma unroll
            for (int i = 0; i < 4; ++i)
#pragma unroll
                for (int j = 0; j < 4; ++j)
                    acc[i][j] = MFMA16(af[i], bfr[j], acc[i][j]);
        }
        __syncthreads();
    }

    const bool kHalf = (col0 + wcol) < 512;
    int cj[4];
    float bias[4];
#pragma unroll
    for (int j = 0; j < 4; ++j) {
        cj[j] = col0 + wcol + j * 16 + lr;
        bias[j] = kHalf ? bk[cj[j]] : bv[cj[j] - 512];
    }
#pragma unroll
    for (int i = 0; i < 4; ++i)
#pragma unroll
        for (int reg = 0; reg < 4; ++reg) {
            float v0 = acc[i][0][reg] + bias[0], v1 = acc[i][1][reg] + bias[1];
            float v2 = acc[i][2][reg] + bias[2], v3 = acc[i][3][reg] + bias[3];
            if (kHalf) {
                float m = fmaxf(fmaxf(v0, v1), fmaxf(v2, v3));
                m = fmaxf(m, __shfl_xor(m, 1)); m = fmaxf(m, __shfl_xor(m, 2));
                m = fmaxf(m, __shfl_xor(m, 4)); m = fmaxf(m, __shfl_xor(m, 8));
                float e0 = __expf(v0 - m), e1 = __expf(v1 - m);
                float e2 = __expf(v2 - m), e3 = __expf(v3 - m);
                float ssum = e0 + e1 + e2 + e3;
                ssum += __shfl_xor(ssum, 1); ssum += __shfl_xor(ssum, 2);
                ssum += __shfl_xor(ssum, 4); ssum += __shfl_xor(ssum, 8);
                float inv = 1.f / ssum;
                v0 = e0 * inv; v1 = e1 * inv; v2 = e2 * inv; v3 = e3 * inv;
            }
            int r = row0 + wrow + i * 16 + 4 * lg + reg;
            float vv[4] = {v0, v1, v2, v3};
#pragma unroll
            for (int j = 0; j < 4; ++j) {
                if (kHalf) kbuf[(size_t)r * Dc + cj[j]] = f2bf(vv[j]);
                else       vbuf[(size_t)r * Dc + cj[j] - 512] = f2bf(vv[j]);
            }
        }
}

// ---------------------------------------------------------------------------
// attn: attn_t[b,h][l][d] = sum_n k[b,n,h,d]*v[b,n,h,l]
// ---------------------------------------------------------------------------
__global__ void __launch_bounds__(512) attn_kernel(const unsigned short* __restrict__ kbuf,
                                                   const unsigned short* __restrict__ vbuf,
                                                   unsigned short* __restrict__ attn_t) {
    __shared__ unsigned short ksh[128][DHc], vsh[128][DHc];
    const int tid = threadIdx.x;
    const int b = blockIdx.x >> 3, h = blockIdx.x & 7;
    const int d = tid >> 3, lb = (tid & 7) * 8;
    const int tok = tid >> 2, c0 = (tid & 3) * 16;
    float acc[8] = {0.f};
    for (int st = 0; st < 2; ++st) {
        __syncthreads();
        size_t o = (size_t)(b * NTOK + st * 128 + tok) * Dc + h * DHc + c0;
        *(u16x8*)&ksh[tok][c0]     = *(const u16x8*)&kbuf[o];
        *(u16x8*)&ksh[tok][c0 + 8] = *(const u16x8*)&kbuf[o + 8];
        *(u16x8*)&vsh[tok][c0]     = *(const u16x8*)&vbuf[o];
        *(u16x8*)&vsh[tok][c0 + 8] = *(const u16x8*)&vbuf[o + 8];
        __syncthreads();
        for (int n = 0; n < 128; ++n) {
            float kd = bf2f(ksh[n][d]);
            u16x4 va = *(const u16x4*)&vsh[n][lb];
            u16x4 vb = *(const u16x4*)&vsh[n][lb + 4];
#pragma unroll
            for (int e = 0; e < 4; ++e) acc[e] += kd * bf2f(va[e]);
#pragma unroll
            for (int e = 0; e < 4; ++e) acc[4 + e] += kd * bf2f(vb[e]);
        }
    }
    size_t base = (size_t)(b * 8 + h) * DHc * DHc;
#pragma unroll
    for (int e = 0; e < 8; ++e)
        attn_t[base + (size_t)(lb + e) * DHc + d] = f2bf(acc[e]);
}

// ---------------------------------------------------------------------------
// gemm1: BM=256, BN=128, BK=64, 512 thr (r5-proven) + row-stats epilogue.
// A1 @ Wqt + bq -> head-softmax -> q @ attn_t -> out1 bf16; stats[cb][row][2]
// ---------------------------------------------------------------------------
__global__ void __launch_bounds__(512, 4) gemm1_kernel(
    const unsigned short* __restrict__ A1, const unsigned short* __restrict__ Wt,
    const float* __restrict__ bq, const unsigned short* __restrict__ attn_t,
    unsigned short* __restrict__ out1, float* __restrict__ stats) {
    __shared__ short lds_s[24576];            // 48 KB: A [0:16384), B [16384:24576)
    short* Alds = lds_s;
    short* Blds = lds_s + 16384;

    const int tid = threadIdx.x, l = tid & 63, w = tid >> 6;
    const int lr = l & 15, lg = l >> 4;
    int raw = blockIdx.x;                      // 1024 blocks, %8==0 -> bijective
    int swz = (raw & 7) * 128 + (raw >> 3);
    int mt = swz >> 2, nt = swz & 3;
    int row0 = mt * 256, col0 = nt * 128;
    int b = row0 >> 13;
    int wrow = (w >> 1) * 64, wcol = (w & 1) * 64;

    f32x4 acc[4][4] = {};

    for (int ks = 0; ks < 8; ++ks) {
#pragma unroll
        for (int i = 0; i < 4; ++i) {          // A: 256 rows x 64 k
            int c = i * 512 + tid;
            int r = c >> 3, kc = c & 7;
            int koff = ks * 64 + ((kc ^ (r & 7)) << 3);
            gload16(A1 + (size_t)(row0 + r) * Dc + koff, &Alds[(i * 8 + w) * 512]);
        }
#pragma unroll
        for (int i = 0; i < 2; ++i) {          // B: 128 rows x 64 k
            int c = i * 512 + tid;
            int r = c >> 3, kc = c & 7;
            int koff = ks * 64 + ((kc ^ (r & 7)) << 3);
            gload16(Wt + (size_t)(col0 + r) * Dc + koff, &Blds[(i * 8 + w) * 512]);
        }
        __syncthreads();
#pragma unroll
        for (int kk = 0; kk < 2; ++kk) {
            int kcw = kk * 4 + lg;
            bf16x8v af[4], bfr[4];
#pragma unroll
            for (int i = 0; i < 4; ++i) {
                int r = wrow + i * 16 + lr;
                af[i] = *(bf16x8v*)&Alds[(r * 8 + (kcw ^ (r & 7))) * 8];
            }
#pragma unroll
            for (int j = 0; j < 4; ++j) {
                int n = wcol + j * 16 + lr;
                bfr[j] = *(bf16x8v*)&Blds[(n * 8 + (kcw ^ (n & 7))) * 8];
            }
#pragma unroll
            for (int i = 0; i < 4; ++i)
#pragma unroll
                for (int j = 0; j < 4; ++j)
                    acc[i][j] = MFMA16(af[i], bfr[j], acc[i][j]);
        }
        __syncthreads();
    }

    float bqv[4];
#pragma unroll
    for (int j = 0; j < 4; ++j) bqv[j] = bq[col0 + wcol + j * 16 + lr];

    // PV B-frags: wave's 64-col block == one head
    int hw = nt * 2 + (wcol >> 6);
    const int cb = hw;                         // stats col-block (same index)
    const unsigned short* at = attn_t + (size_t)(b * 8 + hw) * DHc * DHc;
    short* Qw = lds_s + w * 1024;              // per-wave 16x64 scratch in A region

#pragma unroll
    for (int i = 0; i < 4; ++i) {
        // bias + per-(row,head) softmax (16-lane groups)
#pragma unroll
        for (int reg = 0; reg < 4; ++reg) {
            float v0 = acc[i][0][reg] + bqv[0], v1 = acc[i][1][reg] + bqv[1];
            float v2 = acc[i][2][reg] + bqv[2], v3 = acc[i][3][reg] + bqv[3];
            float m = fmaxf(fmaxf(v0, v1), fmaxf(v2, v3));
            m = fmaxf(m, __shfl_xor(m, 1)); m = fmaxf(m, __shfl_xor(m, 2));
            m = fmaxf(m, __shfl_xor(m, 4)); m = fmaxf(m, __shfl_xor(m, 8));
            float e0 = __expf(v0 - m), e1 = __expf(v1 - m);
            float e2 = __expf(v2 - m), e3 = __expf(v3 - m);
            float ssum = e0 + e1 + e2 + e3;
            ssum += __shfl_xor(ssum, 1); ssum += __shfl_xor(ssum, 2);
            ssum += __shfl_xor(ssum, 4); ssum += __shfl_xor(ssum, 8);
            float inv = 1.f / ssum;
            acc[i][0][reg] = e0 * inv; acc[i][1][reg] = e1 * inv;
            acc[i][2][reg] = e2 * inv; acc[i][3][reg] = e3 * inv;
        }
        // q-frag -> per-wave LDS scratch (swizzled), wave-local
#pragma unroll
        for (int j = 0; j < 4; ++j)
#pragma unroll
            for (int reg = 0; reg < 4; ++reg) {
                int rl = 4 * lg + reg;
                int c = j * 16 + lr;
                Qw[(rl * 8 + ((c >> 3) ^ (rl & 7))) * 8 + (c & 7)] =
                    (short)f2bf(acc[i][j][reg]);
            }
        // PV: 16 rows of this frag x attn (64x64)
        f32x4 acc2[4] = {};
#pragma unroll
        for (int kk = 0; kk < 2; ++kk) {
            int kc = kk * 4 + lg;
            bf16x8v a = *(bf16x8v*)&Qw[(lr * 8 + (kc ^ (lr & 7))) * 8];
            bf16x8v bf2[4];
#pragma unroll
            for (int j = 0; j < 4; ++j)
                bf2[j] = *(const bf16x8v*)&at[(j * 16 + lr) * DHc + kk * 32 + lg * 8];
#pragma unroll
            for (int j = 0; j < 4; ++j)
                acc2[j] = MFMA16(a, bf2[j], acc2[j]);
        }
        // row stats over this wave's 64 cols (sum, sumsq) for fused LN in gemm2m
#pragma unroll
        for (int reg = 0; reg < 4; ++reg) {
            float s  = acc2[0][reg] + acc2[1][reg] + acc2[2][reg] + acc2[3][reg];
            float ss = acc2[0][reg] * acc2[0][reg] + acc2[1][reg] * acc2[1][reg]
                     + acc2[2][reg] * acc2[2][reg] + acc2[3][reg] * acc2[3][reg];
            s += __shfl_xor(s, 1); ss += __shfl_xor(ss, 1);
            s += __shfl_xor(s, 2); ss += __shfl_xor(ss, 2);
            s += __shfl_xor(s, 4); ss += __shfl_xor(ss, 4);
            s += __shfl_xor(s, 8); ss += __shfl_xor(ss, 8);
            if (lr == 0) {
                int r = row0 + wrow + i * 16 + 4 * lg + reg;
                *(float2*)&stats[((size_t)cb * MROWS + r) * 2] = make_float2(s, ss);
            }
        }
#pragma unroll
        for (int j = 0; j < 4; ++j)
#pragma unroll
            for (int reg = 0; reg < 4; ++reg) {
                int r = row0 + wrow + i * 16 + 4 * lg + reg;
                int c = col0 + wcol + j * 16 + lr;
                out1[(size_t)r * Dc + c] = f2bf(acc2[j][reg]);
            }
    }
}

// ---------------------------------------------------------------------------
// gemm2m: fused mid + GEMM2. BM=256, BN=128, BK=64, 512 thr.
// A-staging: out1 -> reg -> LN(stats)+FiLM+SiLU -> bf16 -> swizzled ds_write.
// B via gload16. out = x + A @ oWt + out_b (fp32).
// ---------------------------------------------------------------------------
__global__ void __launch_bounds__(512, 3) gemm2m_kernel(
    const unsigned short* __restrict__ out1, const float* __restrict__ stats,
    const float* __restrict__ lng, const float* __restrict__ lnb,
    const float* __restrict__ eo, const unsigned short* __restrict__ Wt,
    const float* __restrict__ ob, const float* __restrict__ x,
    float* __restrict__ out) {
    __shared__ short lds_s[24576];            // A 32KB | B 16KB
    __shared__ float Gp[Dc], Bp[Dc];          // fused params (4KB)
    short* Alds = lds_s;
    short* Blds = lds_s + 16384;

    const int tid = threadIdx.x, l = tid & 63, w = tid >> 6;
    const int lr = l & 15, lg = l >> 4;
    int raw = blockIdx.x;
    int swz = (raw & 7) * 128 + (raw >> 3);
    int mt = swz >> 2, nt = swz & 3;
    int row0 = mt * 256, col0 = nt * 128;
    int b = row0 >> 13;
    int wrow = (w >> 1) * 64, wcol = (w & 1) * 64;

    // ---- fused-transform params: Gp = g*(1+scale), Bp = b*(1+scale)+shift
    {
        const float* scl = eo + (size_t)b * (2 * Dc);
        const float* shf = scl + Dc;
        float sc = scl[tid], sh = shf[tid];
        Gp[tid] = lng[tid] * (1.f + sc);
        Bp[tid] = lnb[tid] * (1.f + sc) + sh;
    }
    // ---- per-thread staging rows: r = i*64 + (tid>>3); combine 8 stat partials
    const int rl_base = tid >> 3, kc = tid & 7;
    float mean[4], rstd[4];
#pragma unroll
    for (int i = 0; i < 4; ++i) {
        int rg = row0 + i * 64 + rl_base;
        float s = 0.f, ss = 0.f;
#pragma unroll
        for (int cbi = 0; cbi < 8; ++cbi) {
            float2 p = *(const float2*)&stats[((size_t)cbi * MROWS + rg) * 2];
            s += p.x; ss += p.y;
        }
        float mn = s * (1.f / Dc);
        mean[i] = mn;
        rstd[i] = rsqrtf(ss * (1.f / Dc) - mn * mn + 1e-5f);
    }
    __syncthreads();   // Gp/Bp ready

    f32x4 acc[4][4] = {};

    for (int ks = 0; ks < 8; ++ks) {
        int c0 = ks * 64 + kc * 8;
        float4 g0 = *(const float4*)&Gp[c0], g1 = *(const float4*)&Gp[c0 + 4];
        float4 b0 = *(const float4*)&Bp[c0], b1 = *(const float4*)&Bp[c0 + 4];
        float gg[8] = {g0.x, g0.y, g0.z, g0.w, g1.x, g1.y, g1.z, g1.w};
        float bb[8] = {b0.x, b0.y, b0.z, b0.w, b1.x, b1.y, b1.z, b1.w};
#pragma unroll
        for (int i = 0; i < 4; ++i) {          // A: reg-stage + transform
            int rl = i * 64 + rl_base;
            u16x8 v = *(const u16x8*)&out1[(size_t)(row0 + rl) * Dc + c0];
            float a = rstd[i], mn = mean[i];
            bf16x8v o;
#pragma unroll
            for (int j = 0; j < 8; ++j) {
                float t = (bf2f(v[j]) - mn) * a;
                t = t * gg[j] + bb[j];
                o[j] = (short)f2bf(t / (1.f + __expf(-t)));
            }
            *(bf16x8v*)&Alds[(rl * 8 + (kc ^ (rl & 7))) * 8] = o;
        }
#pragma unroll
        for (int i = 0; i < 2; ++i) {          // B: 128 rows x 64 k
            int c = i * 512 + tid;
            int r = c >> 3, kcb = c & 7;
            int koff = ks * 64 + ((kcb ^ (r & 7)) << 3);
            gload16(Wt + (size_t)(col0 + r) * Dc + koff, &Blds[(i * 8 + w) * 512]);
        }
        __syncthreads();
#pragma unroll
        for (int kk = 0; kk < 2; ++kk) {
            int kcw = kk * 4 + lg;
            bf16x8v af[4], bfr[4];
#pragma unroll
            for (int i = 0; i < 4; ++i) {
                int r = wrow + i * 16 + lr;
                af[i] = *(bf16x8v*)&Alds[(r * 8 + (kcw ^ (r & 7))) * 8];
            }
#pragma unroll
            for (int j = 0; j < 4; ++j) {
                int n = wcol + j * 16 + lr;
                bfr[j] = *(bf16x8v*)&Blds[(n * 8 + (kcw ^ (n & 7))) * 8];
            }
#pragma unroll
            for (int i = 0; i < 4; ++i)
#pragma unroll
                for (int j = 0; j < 4; ++j)
                    acc[i][j] = MFMA16(af[i], bfr[j], acc[i][j]);
        }
        __syncthreads();
    }

    float obv[4];
#pragma unroll
    for (int j = 0; j < 4; ++j) obv[j] = ob[col0 + wcol + j * 16 + lr];
#pragma unroll
    for (int i = 0; i < 4; ++i)
#pragma unroll
        for (int j = 0; j < 4; ++j)
#pragma unroll
            for (int reg = 0; reg < 4; ++reg) {
                int r = row0 + wrow + i * 16 + 4 * lg + reg;
                int c = col0 + wcol + j * 16 + lr;
                size_t o = (size_t)r * Dc + c;
                out[o] = acc[i][j][reg] + obv[j] + x[o];
            }
}

// ---------------------------------------------------------------------------
extern "C" void kernel_launch(void* const* d_in, const int* in_sizes, int n_in,
                              void* d_out, int out_size, void* d_ws, size_t ws_size,
                              hipStream_t stream) {
    const float* x      = (const float*)d_in[0];
    const float* xf     = (const float*)d_in[1];
    const float* emb    = (const float*)d_in[2];
    const float* ln_x_g = (const float*)d_in[3];
    const float* ln_x_b = (const float*)d_in[4];
    const float* ln_t_g = (const float*)d_in[5];
    const float* ln_t_b = (const float*)d_in[6];
    const float* Wq     = (const float*)d_in[7];
    const float* bq     = (const float*)d_in[8];
    const float* Wk     = (const float*)d_in[9];
    const float* bk     = (const float*)d_in[10];
    const float* Wv     = (const float*)d_in[11];
    const float* bv     = (const float*)d_in[12];
    const float* emb_W  = (const float*)d_in[13];
    const float* emb_b  = (const float*)d_in[14];
    const float* ln_o_g = (const float*)d_in[15];
    const float* ln_o_b = (const float*)d_in[16];
    const float* out_W  = (const float*)d_in[17];
    const float* out_b  = (const float*)d_in[18];
    float* out = (float*)d_out;

    // ws layout (u16 units unless noted)
    unsigned short* xt   = (unsigned short*)d_ws;                 // 2048*768
    unsigned short* kbuf = xt + (size_t)2048 * TXT;               // 2048*512
    unsigned short* vbuf = kbuf + (size_t)2048 * 512;             // 2048*512
    unsigned short* Wkvt = vbuf + (size_t)2048 * 512;             // 1024*768
    unsigned short* Wqt  = Wkvt + (size_t)1024 * TXT;             // 512*512
    unsigned short* oWt  = Wqt + (size_t)512 * 512;               // 512*512
    unsigned short* attn_t = oWt + (size_t)512 * 512;             // 64*64*64
    float* eo = (float*)(attn_t + (size_t)64 * 64 * 64);          // 8*1024 f32
    unsigned short* out1 = (unsigned short*)(eo + 8 * 1024);      // 65536*512
    unsigned short* A1   = out1 + (size_t)MROWS * Dc;             // 65536*512
    float* stats = (float*)(A1 + (size_t)MROWS * Dc);             // 8*65536*2 f32

    hipLaunchKernelGGL(prep_kernel, dim3(832), dim3(256), 0, stream,
                       Wq, out_W, Wk, Wv, xf, ln_t_g, ln_t_b, Wqt, oWt, Wkvt, xt);
    hipLaunchKernelGGL(emb_kernel, dim3(Bc * 16), dim3(256), 0, stream,
                       emb, emb_W, emb_b, eo);
    hipLaunchKernelGGL(ln_x_kernel, dim3(MROWS / 4), dim3(256), 0, stream,
                       x, ln_x_g, ln_x_b, A1);
    hipLaunchKernelGGL(kvgemm_kernel, dim3(16 * 8), dim3(256), 0, stream,
                       xt, Wkvt, bk, bv, kbuf, vbuf);
    hipLaunchKernelGGL(attn_kernel, dim3(Bc * Hc), dim3(512), 0, stream,
                       kbuf, vbuf, attn_t);
    hipLaunchKernelGGL(gemm1_kernel, dim3(MROWS / 256 * 4), dim3(512), 0, stream,
                       A1, Wqt, bq, attn_t, out1, stats);
    hipLaunchKernelGGL(gemm2m_kernel, dim3(MROWS / 256 * 4), dim3(512), 0, stream,
                       out1, stats, ln_o_g, ln_o_b, eo, oWt, out_b, x, out);
}

// Round 14
// 341.977 us; speedup vs baseline: 1.5502x; 1.0528x over previous
//
#include <hip/hip_runtime.h>
#include <hip/hip_bf16.h>
#include <math.h>

#define Bc 8
#define Tc 8192
#define NTOK 256
#define Dc 512
#define TXT 768
#define TEc 2048
#define Hc 8
#define DHc 64
#define MROWS (Bc * Tc)   // 65536

typedef __attribute__((ext_vector_type(8))) short bf16x8v;
typedef __attribute__((ext_vector_type(8))) unsigned short u16x8;
typedef __attribute__((ext_vector_type(4))) unsigned short u16x4;
typedef __attribute__((ext_vector_type(4))) float f32x4;

#define MFMA16(a, b, c) __builtin_amdgcn_mfma_f32_16x16x32_bf16(a, b, c, 0, 0, 0)

__device__ __forceinline__ unsigned short f2bf(float f) {
    __hip_bfloat16 h = __float2bfloat16(f);
    return __builtin_bit_cast(unsigned short, h);
}
__device__ __forceinline__ float bf2f(unsigned short u) {
    unsigned int x = ((unsigned int)u) << 16;
    return __builtin_bit_cast(float, x);
}

typedef __attribute__((address_space(3))) unsigned int lds_u32_t;
typedef __attribute__((address_space(1))) const unsigned int gbl_u32_t;
__device__ __forceinline__ void gload16(const unsigned short* g, short* l) {
    __builtin_amdgcn_global_load_lds((gbl_u32_t*)g, (lds_u32_t*)l, 16, 0, 0);
}

// ---------------------------------------------------------------------------
// prep: 4 weight transposes + ln_t (832 blocks — r9/r13-proven form)
// ---------------------------------------------------------------------------
__device__ __forceinline__ void transpose_tile(const float* __restrict__ src,
                                               unsigned short* __restrict__ dst,
                                               int N, int rs, int k0, int n0,
                                               char* smem) {
    float (*tile)[65] = (float(*)[65])smem;
    int tx = threadIdx.x & 63, tq = threadIdx.x >> 6;
#pragma unroll
    for (int i = 0; i < 16; ++i) {
        int kk = tq + i * 4;
        tile[kk][tx] = src[(size_t)(k0 + kk) * N + n0 + tx];
    }
    __syncthreads();
#pragma unroll
    for (int i = 0; i < 16; ++i) {
        int nn = tq + i * 4;
        dst[(size_t)(n0 + nn) * rs + k0 + tx] = f2bf(tile[tx][nn]);
    }
}

__global__ void __launch_bounds__(256) prep_kernel(
    const float* __restrict__ Wq, const float* __restrict__ oW,
    const float* __restrict__ Wk, const float* __restrict__ Wv,
    const float* __restrict__ xf, const float* __restrict__ ln_t_g,
    const float* __restrict__ ln_t_b,
    unsigned short* __restrict__ Wqt, unsigned short* __restrict__ oWt,
    unsigned short* __restrict__ Wkvt, unsigned short* __restrict__ xt) {
    __shared__ __align__(16) char smem[16704];
    int bid = blockIdx.x;
    if (bid < 64) {
        transpose_tile(Wq, Wqt, Dc, Dc, (bid >> 3) * 64, (bid & 7) * 64, smem);
        return;
    }
    if (bid < 128) {
        int i = bid - 64;
        transpose_tile(oW, oWt, Dc, Dc, (i >> 3) * 64, (i & 7) * 64, smem);
        return;
    }
    if (bid < 224) {
        int i = bid - 128;
        transpose_tile(Wk, Wkvt, Dc, TXT, (i >> 3) * 64, (i & 7) * 64, smem);
        return;
    }
    if (bid < 320) {
        int i = bid - 224;
        transpose_tile(Wv, Wkvt + (size_t)512 * TXT, Dc, TXT, (i >> 3) * 64, (i & 7) * 64, smem);
        return;
    }
    // ln_t: 512 blocks x 4 rows
    int w = threadIdx.x >> 6, l = threadIdx.x & 63;
    int row = (bid - 320) * 4 + w;
    const float* src = xf + (size_t)row * TXT;
    float4 a0 = *(const float4*)&src[l * 12];
    float4 a1 = *(const float4*)&src[l * 12 + 4];
    float4 a2 = *(const float4*)&src[l * 12 + 8];
    float vals[12] = {a0.x, a0.y, a0.z, a0.w, a1.x, a1.y, a1.z, a1.w,
                      a2.x, a2.y, a2.z, a2.w};
    float s = 0.f, ss = 0.f;
#pragma unroll
    for (int j = 0; j < 12; ++j) { s += vals[j]; ss += vals[j] * vals[j]; }
#pragma unroll
    for (int m = 1; m <= 32; m <<= 1) { s += __shfl_xor(s, m); ss += __shfl_xor(ss, m); }
    float mean = s * (1.f / TXT), var = ss * (1.f / TXT) - mean * mean;
    float rs = rsqrtf(var + 1e-5f);
    unsigned short o[12];
#pragma unroll
    for (int j = 0; j < 12; ++j) {
        int c = l * 12 + j;
        o[j] = f2bf((vals[j] - mean) * rs * ln_t_g[c] + ln_t_b[c]);
    }
    unsigned short* dp = xt + (size_t)row * TXT + l * 12;
    *(u16x4*)&dp[0] = *(u16x4*)&o[0];
    *(u16x4*)&dp[4] = *(u16x4*)&o[4];
    *(u16x4*)&dp[8] = *(u16x4*)&o[8];
}

// ---------------------------------------------------------------------------
// emb: eo[b,:] = silu(emb[b]) @ emb_W + emb_b (standalone, 128 blocks)
// ---------------------------------------------------------------------------
__global__ void __launch_bounds__(256) emb_kernel(const float* __restrict__ emb,
                                                  const float* __restrict__ emb_W,
                                                  const float* __restrict__ emb_b,
                                                  float* __restrict__ eo) {
    __shared__ float s[TEc];
    __shared__ float red[4][64];
    const int tid = threadIdx.x;
    const int b = blockIdx.x >> 4, chunk = blockIdx.x & 15;
#pragma unroll
    for (int j = 0; j < 8; ++j) {
        int idx = tid + 256 * j;
        float e = emb[b * TEc + idx];
        s[idx] = e / (1.f + __expf(-e));
    }
    __syncthreads();
    int c = tid & 63, q = tid >> 6;
    int col = chunk * 64 + c;
    float acc = 0.f;
    for (int kk = q * 512; kk < q * 512 + 512; ++kk)
        acc += s[kk] * emb_W[(size_t)kk * (2 * Dc) + col];
    red[q][c] = acc;
    __syncthreads();
    if (q == 0)
        eo[b * (2 * Dc) + col] = red[0][c] + red[1][c] + red[2][c] + red[3][c] + emb_b[col];
}

// ---------------------------------------------------------------------------
// ln_x: A1 = bf16(LN(x)), one wave per row (zero LDS)
// ---------------------------------------------------------------------------
__global__ void __launch_bounds__(256) ln_x_kernel(const float* __restrict__ x,
                                                   const float* __restrict__ g,
                                                   const float* __restrict__ bt,
                                                   unsigned short* __restrict__ A1) {
    int w = threadIdx.x >> 6, l = threadIdx.x & 63;
    int row = blockIdx.x * 4 + w;
    const float* src = x + (size_t)row * Dc;
    float4 a0 = *(const float4*)&src[l * 8];
    float4 a1 = *(const float4*)&src[l * 8 + 4];
    float vals[8] = {a0.x, a0.y, a0.z, a0.w, a1.x, a1.y, a1.z, a1.w};
    float s = 0.f, ss = 0.f;
#pragma unroll
    for (int j = 0; j < 8; ++j) { s += vals[j]; ss += vals[j] * vals[j]; }
#pragma unroll
    for (int m = 1; m <= 32; m <<= 1) { s += __shfl_xor(s, m); ss += __shfl_xor(ss, m); }
    float mean = s * (1.f / Dc), var = ss * (1.f / Dc) - mean * mean;
    float rs = rsqrtf(var + 1e-5f);
    u16x8 o;
#pragma unroll
    for (int j = 0; j < 8; ++j) {
        int c = l * 8 + j;
        o[j] = f2bf((vals[j] - mean) * rs * g[c] + bt[c]);
    }
    *(u16x8*)&A1[(size_t)row * Dc + l * 8] = o;
}

// ---------------------------------------------------------------------------
// kvgemm: [2048x768] @ [768x1024] -> k (softmaxed) | v  (r3-proven)
// ---------------------------------------------------------------------------
__global__ void __launch_bounds__(256) kvgemm_kernel(
    const unsigned short* __restrict__ xt, const unsigned short* __restrict__ Wkvt,
    const float* __restrict__ bk, const float* __restrict__ bv,
    unsigned short* __restrict__ kbuf, unsigned short* __restrict__ vbuf) {
    __shared__ short lds_s[16384];
    short* Alds = lds_s;
    short* Blds = lds_s + 8192;

    const int tid = threadIdx.x, l = tid & 63, w = tid >> 6;
    const int lr = l & 15, lg = l >> 4;
    int mt = blockIdx.x >> 3, nt = blockIdx.x & 7;
    int row0 = mt * 128, col0 = nt * 128;
    int wrow = (w >> 1) * 64, wcol = (w & 1) * 64;

    f32x4 acc[4][4] = {};
    const int cbase = w * 64 + l;

    for (int ks = 0; ks < 12; ++ks) {
#pragma unroll
        for (int i = 0; i < 4; ++i) {
            int c = i * 256 + cbase;
            int r = c >> 3, kc = c & 7;
            int koff = ks * 64 + ((kc ^ (r & 7)) << 3);
            gload16(xt + (size_t)(row0 + r) * TXT + koff, &Alds[((i * 4 + w) * 64) * 8]);
            gload16(Wkvt + (size_t)(col0 + r) * TXT + koff, &Blds[((i * 4 + w) * 64) * 8]);
        }
        __syncthreads();
#pragma unroll
        for (int kk = 0; kk < 2; ++kk) {
            int kcw = kk * 4 + lg;
            bf16x8v af[4], bfr[4];
#pragma unroll
            for (int i = 0; i < 4; ++i) {
                int r = wrow + i * 16 + lr;
                af[i] = *(bf16x8v*)&Alds[(r * 8 + (kcw ^ (r & 7))) * 8];
            }
#pragma unroll
            for (int j = 0; j < 4; ++j) {
                int n = wcol + j * 16 + lr;
                bfr[j] = *(bf16x8v*)&Blds[(n * 8 + (kcw ^ (n & 7))) * 8];
            }
#pragma unroll
            for (int i = 0; i < 4; ++i)
#pragma unroll
                for (int j = 0; j < 4; ++j)
                    acc[i][j] = MFMA16(af[i], bfr[j], acc[i][j]);
        }
        __syncthreads();
    }

    const bool kHalf = (col0 + wcol) < 512;
    int cj[4];
    float bias[4];
#pragma unroll
    for (int j = 0; j < 4; ++j) {
        cj[j] = col0 + wcol + j * 16 + lr;
        bias[j] = kHalf ? bk[cj[j]] : bv[cj[j] - 512];
    }
#pragma unroll
    for (int i = 0; i < 4; ++i)
#pragma unroll
        for (int reg = 0; reg < 4; ++reg) {
            float v0 = acc[i][0][reg] + bias[0], v1 = acc[i][1][reg] + bias[1];
            float v2 = acc[i][2][reg] + bias[2], v3 = acc[i][3][reg] + bias[3];
            if (kHalf) {
                float m = fmaxf(fmaxf(v0, v1), fmaxf(v2, v3));
                m = fmaxf(m, __shfl_xor(m, 1)); m = fmaxf(m, __shfl_xor(m, 2));
                m = fmaxf(m, __shfl_xor(m, 4)); m = fmaxf(m, __shfl_xor(m, 8));
                float e0 = __expf(v0 - m), e1 = __expf(v1 - m);
                float e2 = __expf(v2 - m), e3 = __expf(v3 - m);
                float ssum = e0 + e1 + e2 + e3;
                ssum += __shfl_xor(ssum, 1); ssum += __shfl_xor(ssum, 2);
                ssum += __shfl_xor(ssum, 4); ssum += __shfl_xor(ssum, 8);
                float inv = 1.f / ssum;
                v0 = e0 * inv; v1 = e1 * inv; v2 = e2 * inv; v3 = e3 * inv;
            }
            int r = row0 + wrow + i * 16 + 4 * lg + reg;
            float vv[4] = {v0, v1, v2, v3};
#pragma unroll
            for (int j = 0; j < 4; ++j) {
                if (kHalf) kbuf[(size_t)r * Dc + cj[j]] = f2bf(vv[j]);
                else       vbuf[(size_t)r * Dc + cj[j] - 512] = f2bf(vv[j]);
            }
        }
}

// ---------------------------------------------------------------------------
// attn: attn_t[b,h][l][d] = sum_n k[b,n,h,d]*v[b,n,h,l]
// ---------------------------------------------------------------------------
__global__ void __launch_bounds__(512) attn_kernel(const unsigned short* __restrict__ kbuf,
                                                   const unsigned short* __restrict__ vbuf,
                                                   unsigned short* __restrict__ attn_t) {
    __shared__ unsigned short ksh[128][DHc], vsh[128][DHc];
    const int tid = threadIdx.x;
    const int b = blockIdx.x >> 3, h = blockIdx.x & 7;
    const int d = tid >> 3, lb = (tid & 7) * 8;
    const int tok = tid >> 2, c0 = (tid & 3) * 16;
    float acc[8] = {0.f};
    for (int st = 0; st < 2; ++st) {
        __syncthreads();
        size_t o = (size_t)(b * NTOK + st * 128 + tok) * Dc + h * DHc + c0;
        *(u16x8*)&ksh[tok][c0]     = *(const u16x8*)&kbuf[o];
        *(u16x8*)&ksh[tok][c0 + 8] = *(const u16x8*)&kbuf[o + 8];
        *(u16x8*)&vsh[tok][c0]     = *(const u16x8*)&vbuf[o];
        *(u16x8*)&vsh[tok][c0 + 8] = *(const u16x8*)&vbuf[o + 8];
        __syncthreads();
        for (int n = 0; n < 128; ++n) {
            float kd = bf2f(ksh[n][d]);
            u16x4 va = *(const u16x4*)&vsh[n][lb];
            u16x4 vb = *(const u16x4*)&vsh[n][lb + 4];
#pragma unroll
            for (int e = 0; e < 4; ++e) acc[e] += kd * bf2f(va[e]);
#pragma unroll
            for (int e = 0; e < 4; ++e) acc[4 + e] += kd * bf2f(vb[e]);
        }
    }
    size_t base = (size_t)(b * 8 + h) * DHc * DHc;
#pragma unroll
    for (int e = 0; e < 8; ++e)
        attn_t[base + (size_t)(lb + e) * DHc + d] = f2bf(acc[e]);
}

// ---------------------------------------------------------------------------
// gemm1: BM=256, BN=128, BK=64, 512 thr (r5-proven, no stats).
// A1 @ Wqt + bq -> head-softmax -> q @ attn_t -> out1 bf16
// ---------------------------------------------------------------------------
__global__ void __launch_bounds__(512, 4) gemm1_kernel(
    const unsigned short* __restrict__ A1, const unsigned short* __restrict__ Wt,
    const float* __restrict__ bq, const unsigned short* __restrict__ attn_t,
    unsigned short* __restrict__ out1) {
    __shared__ short lds_s[24576];            // 48 KB: A [0:16384), B [16384:24576)
    short* Alds = lds_s;
    short* Blds = lds_s + 16384;

    const int tid = threadIdx.x, l = tid & 63, w = tid >> 6;
    const int lr = l & 15, lg = l >> 4;
    int raw = blockIdx.x;                      // 1024 blocks, %8==0 -> bijective
    int swz = (raw & 7) * 128 + (raw >> 3);
    int mt = swz >> 2, nt = swz & 3;
    int row0 = mt * 256, col0 = nt * 128;
    int b = row0 >> 13;
    int wrow = (w >> 1) * 64, wcol = (w & 1) * 64;

    f32x4 acc[4][4] = {};

    for (int ks = 0; ks < 8; ++ks) {
#pragma unroll
        for (int i = 0; i < 4; ++i) {          // A: 256 rows x 64 k
            int c = i * 512 + tid;
            int r = c >> 3, kc = c & 7;
            int koff = ks * 64 + ((kc ^ (r & 7)) << 3);
            gload16(A1 + (size_t)(row0 + r) * Dc + koff, &Alds[(i * 8 + w) * 512]);
        }
#pragma unroll
        for (int i = 0; i < 2; ++i) {          // B: 128 rows x 64 k
            int c = i * 512 + tid;
            int r = c >> 3, kc = c & 7;
            int koff = ks * 64 + ((kc ^ (r & 7)) << 3);
            gload16(Wt + (size_t)(col0 + r) * Dc + koff, &Blds[(i * 8 + w) * 512]);
        }
        __syncthreads();
#pragma unroll
        for (int kk = 0; kk < 2; ++kk) {
            int kcw = kk * 4 + lg;
            bf16x8v af[4], bfr[4];
#pragma unroll
            for (int i = 0; i < 4; ++i) {
                int r = wrow + i * 16 + lr;
                af[i] = *(bf16x8v*)&Alds[(r * 8 + (kcw ^ (r & 7))) * 8];
            }
#pragma unroll
            for (int j = 0; j < 4; ++j) {
                int n = wcol + j * 16 + lr;
                bfr[j] = *(bf16x8v*)&Blds[(n * 8 + (kcw ^ (n & 7))) * 8];
            }
#pragma unroll
            for (int i = 0; i < 4; ++i)
#pragma unroll
                for (int j = 0; j < 4; ++j)
                    acc[i][j] = MFMA16(af[i], bfr[j], acc[i][j]);
        }
        __syncthreads();
    }

    float bqv[4];
#pragma unroll
    for (int j = 0; j < 4; ++j) bqv[j] = bq[col0 + wcol + j * 16 + lr];

    // PV B-frags: wave's 64-col block == one head
    int hw = nt * 2 + (wcol >> 6);
    const unsigned short* at = attn_t + (size_t)(b * 8 + hw) * DHc * DHc;
    short* Qw = lds_s + w * 1024;              // per-wave 16x64 scratch in A region

#pragma unroll
    for (int i = 0; i < 4; ++i) {
        // bias + per-(row,head) softmax (16-lane groups)
#pragma unroll
        for (int reg = 0; reg < 4; ++reg) {
            float v0 = acc[i][0][reg] + bqv[0], v1 = acc[i][1][reg] + bqv[1];
            float v2 = acc[i][2][reg] + bqv[2], v3 = acc[i][3][reg] + bqv[3];
            float m = fmaxf(fmaxf(v0, v1), fmaxf(v2, v3));
            m = fmaxf(m, __shfl_xor(m, 1)); m = fmaxf(m, __shfl_xor(m, 2));
            m = fmaxf(m, __shfl_xor(m, 4)); m = fmaxf(m, __shfl_xor(m, 8));
            float e0 = __expf(v0 - m), e1 = __expf(v1 - m);
            float e2 = __expf(v2 - m), e3 = __expf(v3 - m);
            float ssum = e0 + e1 + e2 + e3;
            ssum += __shfl_xor(ssum, 1); ssum += __shfl_xor(ssum, 2);
            ssum += __shfl_xor(ssum, 4); ssum += __shfl_xor(ssum, 8);
            float inv = 1.f / ssum;
            acc[i][0][reg] = e0 * inv; acc[i][1][reg] = e1 * inv;
            acc[i][2][reg] = e2 * inv; acc[i][3][reg] = e3 * inv;
        }
        // q-frag -> per-wave LDS scratch (swizzled), wave-local
#pragma unroll
        for (int j = 0; j < 4; ++j)
#pragma unroll
            for (int reg = 0; reg < 4; ++reg) {
                int rl = 4 * lg + reg;
                int c = j * 16 + lr;
                Qw[(rl * 8 + ((c >> 3) ^ (rl & 7))) * 8 + (c & 7)] =
                    (short)f2bf(acc[i][j][reg]);
            }
        // PV: 16 rows of this frag x attn (64x64)
        f32x4 acc2[4] = {};
#pragma unroll
        for (int kk = 0; kk < 2; ++kk) {
            int kc = kk * 4 + lg;
            bf16x8v a = *(bf16x8v*)&Qw[(lr * 8 + (kc ^ (lr & 7))) * 8];
            bf16x8v bf2[4];
#pragma unroll
            for (int j = 0; j < 4; ++j)
                bf2[j] = *(const bf16x8v*)&at[(j * 16 + lr) * DHc + kk * 32 + lg * 8];
#pragma unroll
            for (int j = 0; j < 4; ++j)
                acc2[j] = MFMA16(a, bf2[j], acc2[j]);
        }
#pragma unroll
        for (int j = 0; j < 4; ++j)
#pragma unroll
            for (int reg = 0; reg < 4; ++reg) {
                int r = row0 + wrow + i * 16 + 4 * lg + reg;
                int c = col0 + wcol + j * 16 + lr;
                out1[(size_t)r * Dc + c] = f2bf(acc2[j][reg]);
            }
    }
}

// ---------------------------------------------------------------------------
// mid: A2 = bf16( silu( LN(out1)*(1+scale)+shift ) )  (r3-proven)
// ---------------------------------------------------------------------------
__global__ void __launch_bounds__(256) mid_kernel(const unsigned short* __restrict__ out1,
                                                  const float* __restrict__ eo,
                                                  const float* __restrict__ g,
                                                  const float* __restrict__ bt,
                                                  unsigned short* __restrict__ A2) {
    int w = threadIdx.x >> 6, l = threadIdx.x & 63;
    int row = blockIdx.x * 4 + w;
    int b = row >> 13;
    u16x8 iv = *(const u16x8*)&out1[(size_t)row * Dc + l * 8];
    float vals[8];
    float s = 0.f, ss = 0.f;
#pragma unroll
    for (int j = 0; j < 8; ++j) {
        vals[j] = bf2f(iv[j]);
        s += vals[j]; ss += vals[j] * vals[j];
    }
#pragma unroll
    for (int m = 1; m <= 32; m <<= 1) { s += __shfl_xor(s, m); ss += __shfl_xor(ss, m); }
    float mean = s * (1.f / Dc), var = ss * (1.f / Dc) - mean * mean;
    float rs = rsqrtf(var + 1e-5f);
    const float* scl = eo + (size_t)b * (2 * Dc);
    const float* shf = scl + Dc;
    u16x8 o;
#pragma unroll
    for (int j = 0; j < 8; ++j) {
        int c = l * 8 + j;
        float t = (vals[j] - mean) * rs * g[c] + bt[c];
        t = t * (1.f + scl[c]) + shf[c];
        t = t / (1.f + __expf(-t));
        o[j] = f2bf(t);
    }
    *(u16x8*)&A2[(size_t)row * Dc + l * 8] = o;
}

// ---------------------------------------------------------------------------
// gemm2: BM=256, BN=128, BK=64, 512 thr (r5-proven) + x L2-touch prefetch
// during K-steps 4..7. out = x + A2 @ oWt + out_b (fp32)
// ---------------------------------------------------------------------------
__global__ void __launch_bounds__(512, 4) gemm2_kernel(
    const unsigned short* __restrict__ A2, const unsigned short* __restrict__ Wt,
    const float* __restrict__ ob, const float* __restrict__ x,
    float* __restrict__ out) {
    __shared__ short lds_s[24576];
    short* Alds = lds_s;
    short* Blds = lds_s + 16384;

    const int tid = threadIdx.x, l = tid & 63, w = tid >> 6;
    const int lr = l & 15, lg = l >> 4;
    int raw = blockIdx.x;
    int swz = (raw & 7) * 128 + (raw >> 3);
    int mt = swz >> 2, nt = swz & 3;
    int row0 = mt * 256, col0 = nt * 128;
    int wrow = (w >> 1) * 64, wcol = (w & 1) * 64;

    f32x4 acc[4][4] = {};
    const volatile float* xv = x;   // volatile: touches can't CSE into epilogue

    for (int ks = 0; ks < 8; ++ks) {
#pragma unroll
        for (int i = 0; i < 4; ++i) {
            int c = i * 512 + tid;
            int r = c >> 3, kc = c & 7;
            int koff = ks * 64 + ((kc ^ (r & 7)) << 3);
            gload16(A2 + (size_t)(row0 + r) * Dc + koff, &Alds[(i * 8 + w) * 512]);
        }
#pragma unroll
        for (int i = 0; i < 2; ++i) {
            int c = i * 512 + tid;
            int r = c >> 3, kc = c & 7;
            int koff = ks * 64 + ((kc ^ (r & 7)) << 3);
            gload16(Wt + (size_t)(col0 + r) * Dc + koff, &Blds[(i * 8 + w) * 512]);
        }
        // L2 touch-prefetch of this block's x tile (epilogue residual), 1/4 per step
        if (ks >= 4) {
            int i = ks - 4;
            size_t xbase = (size_t)(row0 + wrow + i * 16 + 4 * lg) * Dc + col0 + wcol + lr;
#pragma unroll
            for (int reg = 0; reg < 4; ++reg)
#pragma unroll
                for (int j = 0; j < 4; ++j) {
                    float t = xv[xbase + (size_t)reg * Dc + j * 16];
                    asm volatile("" :: "v"(t));
                }
        }
        __syncthreads();
#pragma unroll
        for (int kk = 0; kk < 2; ++kk) {
            int kcw = kk * 4 + lg;
            bf16x8v af[4], bfr[4];
#pragma unroll
            for (int i = 0; i < 4; ++i) {
                int r = wrow + i * 16 + lr;
                af[i] = *(bf16x8v*)&Alds[(r * 8 + (kcw ^ (r & 7))) * 8];
            }
#pragma unroll
            for (int j = 0; j < 4; ++j) {
                int n = wcol + j * 16 + lr;
                bfr[j] = *(bf16x8v*)&Blds[(n * 8 + (kcw ^ (n & 7))) * 8];
            }
#pragma unroll
            for (int i = 0; i < 4; ++i)
#pragma unroll
                for (int j = 0; j < 4; ++j)
                    acc[i][j] = MFMA16(af[i], bfr[j], acc[i][j]);
        }
        __syncthreads();
    }

    float obv[4];
#pragma unroll
    for (int j = 0; j < 4; ++j) obv[j] = ob[col0 + wcol + j * 16 + lr];
#pragma unroll
    for (int i = 0; i < 4; ++i)
#pragma unroll
        for (int j = 0; j < 4; ++j)
#pragma unroll
            for (int reg = 0; reg < 4; ++reg) {
                int r = row0 + wrow + i * 16 + 4 * lg + reg;
                int c = col0 + wcol + j * 16 + lr;
                size_t o = (size_t)r * Dc + c;
                out[o] = acc[i][j][reg] + obv[j] + x[o];
            }
}

// ---------------------------------------------------------------------------
extern "C" void kernel_launch(void* const* d_in, const int* in_sizes, int n_in,
                              void* d_out, int out_size, void* d_ws, size_t ws_size,
                              hipStream_t stream) {
    const float* x      = (const float*)d_in[0];
    const float* xf     = (const float*)d_in[1];
    const float* emb    = (const float*)d_in[2];
    const float* ln_x_g = (const float*)d_in[3];
    const float* ln_x_b = (const float*)d_in[4];
    const float* ln_t_g = (const float*)d_in[5];
    const float* ln_t_b = (const float*)d_in[6];
    const float* Wq     = (const float*)d_in[7];
    const float* bq     = (const float*)d_in[8];
    const float* Wk     = (const float*)d_in[9];
    const float* bk     = (const float*)d_in[10];
    const float* Wv     = (const float*)d_in[11];
    const float* bv     = (const float*)d_in[12];
    const float* emb_W  = (const float*)d_in[13];
    const float* emb_b  = (const float*)d_in[14];
    const float* ln_o_g = (const float*)d_in[15];
    const float* ln_o_b = (const float*)d_in[16];
    const float* out_W  = (const float*)d_in[17];
    const float* out_b  = (const float*)d_in[18];
    float* out = (float*)d_out;

    // ws layout (u16 units unless noted)
    unsigned short* xt   = (unsigned short*)d_ws;                 // 2048*768
    unsigned short* kbuf = xt + (size_t)2048 * TXT;               // 2048*512
    unsigned short* vbuf = kbuf + (size_t)2048 * 512;             // 2048*512
    unsigned short* Wkvt = vbuf + (size_t)2048 * 512;             // 1024*768
    unsigned short* Wqt  = Wkvt + (size_t)1024 * TXT;             // 512*512
    unsigned short* oWt  = Wqt + (size_t)512 * 512;               // 512*512
    unsigned short* attn_t = oWt + (size_t)512 * 512;             // 64*64*64
    float* eo = (float*)(attn_t + (size_t)64 * 64 * 64);          // 8*1024 f32
    unsigned short* out1 = (unsigned short*)(eo + 8 * 1024);      // 65536*512
    unsigned short* A1   = out1 + (size_t)MROWS * Dc;             // 65536*512
    unsigned short* A2   = A1;                                    // overlay (A1 dead)

    hipLaunchKernelGGL(prep_kernel, dim3(832), dim3(256), 0, stream,
                       Wq, out_W, Wk, Wv, xf, ln_t_g, ln_t_b, Wqt, oWt, Wkvt, xt);
    hipLaunchKernelGGL(ln_x_kernel, dim3(MROWS / 4), dim3(256), 0, stream,
                       x, ln_x_g, ln_x_b, A1);
    hipLaunchKernelGGL(kvgemm_kernel, dim3(16 * 8), dim3(256), 0, stream,
                       xt, Wkvt, bk, bv, kbuf, vbuf);
    hipLaunchKernelGGL(attn_kernel, dim3(Bc * Hc), dim3(512), 0, stream,
                       kbuf, vbuf, attn_t);
    hipLaunchKernelGGL(emb_kernel, dim3(Bc * 16), dim3(256), 0, stream,
                       emb, emb_W, emb_b, eo);
    hipLaunchKernelGGL(gemm1_kernel, dim3(MROWS / 256 * 4), dim3(512), 0, stream,
                       A1, Wqt, bq, attn_t, out1);
    hipLaunchKernelGGL(mid_kernel, dim3(MROWS / 4), dim3(256), 0, stream,
                       out1, eo, ln_o_g, ln_o_b, A2);
    hipLaunchKernelGGL(gemm2_kernel, dim3(MROWS / 256 * 4), dim3(512), 0, stream,
                       A2, oWt, out_b, x, out);
}

// Round 15
// 283.232 us; speedup vs baseline: 1.8717x; 1.2074x over previous
//
#include <hip/hip_runtime.h>
#include <hip/hip_bf16.h>
#include <math.h>

#define Bc 8
#define Tc 8192
#define NTOK 256
#define Dc 512
#define TXT 768
#define TEc 2048
#define Hc 8
#define DHc 64
#define MROWS (Bc * Tc)   // 65536

typedef __attribute__((ext_vector_type(8))) short bf16x8v;
typedef __attribute__((ext_vector_type(8))) unsigned short u16x8;
typedef __attribute__((ext_vector_type(4))) unsigned short u16x4;
typedef __attribute__((ext_vector_type(4))) float f32x4;

#define MFMA16(a, b, c) __builtin_amdgcn_mfma_f32_16x16x32_bf16(a, b, c, 0, 0, 0)

__device__ __forceinline__ unsigned short f2bf(float f) {
    __hip_bfloat16 h = __float2bfloat16(f);
    return __builtin_bit_cast(unsigned short, h);
}
__device__ __forceinline__ float bf2f(unsigned short u) {
    unsigned int x = ((unsigned int)u) << 16;
    return __builtin_bit_cast(float, x);
}

typedef __attribute__((address_space(3))) unsigned int lds_u32_t;
typedef __attribute__((address_space(1))) const unsigned int gbl_u32_t;
__device__ __forceinline__ void gload16(const unsigned short* g, short* l) {
    __builtin_amdgcn_global_load_lds((gbl_u32_t*)g, (lds_u32_t*)l, 16, 0, 0);
}

// ---------------------------------------------------------------------------
// prep: 4 weight transposes + ln_t (832 blocks — r5-champion form)
// ---------------------------------------------------------------------------
__device__ __forceinline__ void transpose_tile(const float* __restrict__ src,
                                               unsigned short* __restrict__ dst,
                                               int N, int rs, int k0, int n0,
                                               char* smem) {
    float (*tile)[65] = (float(*)[65])smem;
    int tx = threadIdx.x & 63, tq = threadIdx.x >> 6;
#pragma unroll
    for (int i = 0; i < 16; ++i) {
        int kk = tq + i * 4;
        tile[kk][tx] = src[(size_t)(k0 + kk) * N + n0 + tx];
    }
    __syncthreads();
#pragma unroll
    for (int i = 0; i < 16; ++i) {
        int nn = tq + i * 4;
        dst[(size_t)(n0 + nn) * rs + k0 + tx] = f2bf(tile[tx][nn]);
    }
}

__global__ void __launch_bounds__(256) prep_kernel(
    const float* __restrict__ Wq, const float* __restrict__ oW,
    const float* __restrict__ Wk, const float* __restrict__ Wv,
    const float* __restrict__ xf, const float* __restrict__ ln_t_g,
    const float* __restrict__ ln_t_b,
    unsigned short* __restrict__ Wqt, unsigned short* __restrict__ oWt,
    unsigned short* __restrict__ Wkvt, unsigned short* __restrict__ xt) {
    __shared__ __align__(16) char smem[16704];
    int bid = blockIdx.x;
    if (bid < 64) {
        transpose_tile(Wq, Wqt, Dc, Dc, (bid >> 3) * 64, (bid & 7) * 64, smem);
        return;
    }
    if (bid < 128) {
        int i = bid - 64;
        transpose_tile(oW, oWt, Dc, Dc, (i >> 3) * 64, (i & 7) * 64, smem);
        return;
    }
    if (bid < 224) {
        int i = bid - 128;
        transpose_tile(Wk, Wkvt, Dc, TXT, (i >> 3) * 64, (i & 7) * 64, smem);
        return;
    }
    if (bid < 320) {
        int i = bid - 224;
        transpose_tile(Wv, Wkvt + (size_t)512 * TXT, Dc, TXT, (i >> 3) * 64, (i & 7) * 64, smem);
        return;
    }
    // ln_t: 512 blocks x 4 rows
    int w = threadIdx.x >> 6, l = threadIdx.x & 63;
    int row = (bid - 320) * 4 + w;
    const float* src = xf + (size_t)row * TXT;
    float4 a0 = *(const float4*)&src[l * 12];
    float4 a1 = *(const float4*)&src[l * 12 + 4];
    float4 a2 = *(const float4*)&src[l * 12 + 8];
    float vals[12] = {a0.x, a0.y, a0.z, a0.w, a1.x, a1.y, a1.z, a1.w,
                      a2.x, a2.y, a2.z, a2.w};
    float s = 0.f, ss = 0.f;
#pragma unroll
    for (int j = 0; j < 12; ++j) { s += vals[j]; ss += vals[j] * vals[j]; }
#pragma unroll
    for (int m = 1; m <= 32; m <<= 1) { s += __shfl_xor(s, m); ss += __shfl_xor(ss, m); }
    float mean = s * (1.f / TXT), var = ss * (1.f / TXT) - mean * mean;
    float rs = rsqrtf(var + 1e-5f);
    unsigned short o[12];
#pragma unroll
    for (int j = 0; j < 12; ++j) {
        int c = l * 12 + j;
        o[j] = f2bf((vals[j] - mean) * rs * ln_t_g[c] + ln_t_b[c]);
    }
    unsigned short* dp = xt + (size_t)row * TXT + l * 12;
    *(u16x4*)&dp[0] = *(u16x4*)&o[0];
    *(u16x4*)&dp[4] = *(u16x4*)&o[4];
    *(u16x4*)&dp[8] = *(u16x4*)&o[8];
}

// ---------------------------------------------------------------------------
// emb: eo[b,:] = silu(emb[b]) @ emb_W + emb_b (standalone, 128 blocks)
// ---------------------------------------------------------------------------
__global__ void __launch_bounds__(256) emb_kernel(const float* __restrict__ emb,
                                                  const float* __restrict__ emb_W,
                                                  const float* __restrict__ emb_b,
                                                  float* __restrict__ eo) {
    __shared__ float s[TEc];
    __shared__ float red[4][64];
    const int tid = threadIdx.x;
    const int b = blockIdx.x >> 4, chunk = blockIdx.x & 15;
#pragma unroll
    for (int j = 0; j < 8; ++j) {
        int idx = tid + 256 * j;
        float e = emb[b * TEc + idx];
        s[idx] = e / (1.f + __expf(-e));
    }
    __syncthreads();
    int c = tid & 63, q = tid >> 6;
    int col = chunk * 64 + c;
    float acc = 0.f;
    for (int kk = q * 512; kk < q * 512 + 512; ++kk)
        acc += s[kk] * emb_W[(size_t)kk * (2 * Dc) + col];
    red[q][c] = acc;
    __syncthreads();
    if (q == 0)
        eo[b * (2 * Dc) + col] = red[0][c] + red[1][c] + red[2][c] + red[3][c] + emb_b[col];
}

// ---------------------------------------------------------------------------
// ln_x: A1 = bf16(LN(x)), one wave per row (zero LDS)
// ---------------------------------------------------------------------------
__global__ void __launch_bounds__(256) ln_x_kernel(const float* __restrict__ x,
                                                   const float* __restrict__ g,
                                                   const float* __restrict__ bt,
                                                   unsigned short* __restrict__ A1) {
    int w = threadIdx.x >> 6, l = threadIdx.x & 63;
    int row = blockIdx.x * 4 + w;
    const float* src = x + (size_t)row * Dc;
    float4 a0 = *(const float4*)&src[l * 8];
    float4 a1 = *(const float4*)&src[l * 8 + 4];
    float vals[8] = {a0.x, a0.y, a0.z, a0.w, a1.x, a1.y, a1.z, a1.w};
    float s = 0.f, ss = 0.f;
#pragma unroll
    for (int j = 0; j < 8; ++j) { s += vals[j]; ss += vals[j] * vals[j]; }
#pragma unroll
    for (int m = 1; m <= 32; m <<= 1) { s += __shfl_xor(s, m); ss += __shfl_xor(ss, m); }
    float mean = s * (1.f / Dc), var = ss * (1.f / Dc) - mean * mean;
    float rs = rsqrtf(var + 1e-5f);
    u16x8 o;
#pragma unroll
    for (int j = 0; j < 8; ++j) {
        int c = l * 8 + j;
        o[j] = f2bf((vals[j] - mean) * rs * g[c] + bt[c]);
    }
    *(u16x8*)&A1[(size_t)row * Dc + l * 8] = o;
}

// ---------------------------------------------------------------------------
// kvgemm: [2048x768] @ [768x1024] -> k (softmaxed) | v  (r3-proven)
// ---------------------------------------------------------------------------
__global__ void __launch_bounds__(256) kvgemm_kernel(
    const unsigned short* __restrict__ xt, const unsigned short* __restrict__ Wkvt,
    const float* __restrict__ bk, const float* __restrict__ bv,
    unsigned short* __restrict__ kbuf, unsigned short* __restrict__ vbuf) {
    __shared__ short lds_s[16384];
    short* Alds = lds_s;
    short* Blds = lds_s + 8192;

    const int tid = threadIdx.x, l = tid & 63, w = tid >> 6;
    const int lr = l & 15, lg = l >> 4;
    int mt = blockIdx.x >> 3, nt = blockIdx.x & 7;
    int row0 = mt * 128, col0 = nt * 128;
    int wrow = (w >> 1) * 64, wcol = (w & 1) * 64;

    f32x4 acc[4][4] = {};
    const int cbase = w * 64 + l;

    for (int ks = 0; ks < 12; ++ks) {
#pragma unroll
        for (int i = 0; i < 4; ++i) {
            int c = i * 256 + cbase;
            int r = c >> 3, kc = c & 7;
            int koff = ks * 64 + ((kc ^ (r & 7)) << 3);
            gload16(xt + (size_t)(row0 + r) * TXT + koff, &Alds[((i * 4 + w) * 64) * 8]);
            gload16(Wkvt + (size_t)(col0 + r) * TXT + koff, &Blds[((i * 4 + w) * 64) * 8]);
        }
        __syncthreads();
#pragma unroll
        for (int kk = 0; kk < 2; ++kk) {
            int kcw = kk * 4 + lg;
            bf16x8v af[4], bfr[4];
#pragma unroll
            for (int i = 0; i < 4; ++i) {
                int r = wrow + i * 16 + lr;
                af[i] = *(bf16x8v*)&Alds[(r * 8 + (kcw ^ (r & 7))) * 8];
            }
#pragma unroll
            for (int j = 0; j < 4; ++j) {
                int n = wcol + j * 16 + lr;
                bfr[j] = *(bf16x8v*)&Blds[(n * 8 + (kcw ^ (n & 7))) * 8];
            }
#pragma unroll
            for (int i = 0; i < 4; ++i)
#pragma unroll
                for (int j = 0; j < 4; ++j)
                    acc[i][j] = MFMA16(af[i], bfr[j], acc[i][j]);
        }
        __syncthreads();
    }

    const bool kHalf = (col0 + wcol) < 512;
    int cj[4];
    float bias[4];
#pragma unroll
    for (int j = 0; j < 4; ++j) {
        cj[j] = col0 + wcol + j * 16 + lr;
        bias[j] = kHalf ? bk[cj[j]] : bv[cj[j] - 512];
    }
#pragma unroll
    for (int i = 0; i < 4; ++i)
#pragma unroll
        for (int reg = 0; reg < 4; ++reg) {
            float v0 = acc[i][0][reg] + bias[0], v1 = acc[i][1][reg] + bias[1];
            float v2 = acc[i][2][reg] + bias[2], v3 = acc[i][3][reg] + bias[3];
            if (kHalf) {
                float m = fmaxf(fmaxf(v0, v1), fmaxf(v2, v3));
                m = fmaxf(m, __shfl_xor(m, 1)); m = fmaxf(m, __shfl_xor(m, 2));
                m = fmaxf(m, __shfl_xor(m, 4)); m = fmaxf(m, __shfl_xor(m, 8));
                float e0 = __expf(v0 - m), e1 = __expf(v1 - m);
                float e2 = __expf(v2 - m), e3 = __expf(v3 - m);
                float ssum = e0 + e1 + e2 + e3;
                ssum += __shfl_xor(ssum, 1); ssum += __shfl_xor(ssum, 2);
                ssum += __shfl_xor(ssum, 4); ssum += __shfl_xor(ssum, 8);
                float inv = 1.f / ssum;
                v0 = e0 * inv; v1 = e1 * inv; v2 = e2 * inv; v3 = e3 * inv;
            }
            int r = row0 + wrow + i * 16 + 4 * lg + reg;
            float vv[4] = {v0, v1, v2, v3};
#pragma unroll
            for (int j = 0; j < 4; ++j) {
                if (kHalf) kbuf[(size_t)r * Dc + cj[j]] = f2bf(vv[j]);
                else       vbuf[(size_t)r * Dc + cj[j] - 512] = f2bf(vv[j]);
            }
        }
}

// ---------------------------------------------------------------------------
// attn: attn_t[b,h][l][d] = sum_n k[b,n,h,d]*v[b,n,h,l]
// ---------------------------------------------------------------------------
__global__ void __launch_bounds__(512) attn_kernel(const unsigned short* __restrict__ kbuf,
                                                   const unsigned short* __restrict__ vbuf,
                                                   unsigned short* __restrict__ attn_t) {
    __shared__ unsigned short ksh[128][DHc], vsh[128][DHc];
    const int tid = threadIdx.x;
    const int b = blockIdx.x >> 3, h = blockIdx.x & 7;
    const int d = tid >> 3, lb = (tid & 7) * 8;
    const int tok = tid >> 2, c0 = (tid & 3) * 16;
    float acc[8] = {0.f};
    for (int st = 0; st < 2; ++st) {
        __syncthreads();
        size_t o = (size_t)(b * NTOK + st * 128 + tok) * Dc + h * DHc + c0;
        *(u16x8*)&ksh[tok][c0]     = *(const u16x8*)&kbuf[o];
        *(u16x8*)&ksh[tok][c0 + 8] = *(const u16x8*)&kbuf[o + 8];
        *(u16x8*)&vsh[tok][c0]     = *(const u16x8*)&vbuf[o];
        *(u16x8*)&vsh[tok][c0 + 8] = *(const u16x8*)&vbuf[o + 8];
        __syncthreads();
        for (int n = 0; n < 128; ++n) {
            float kd = bf2f(ksh[n][d]);
            u16x4 va = *(const u16x4*)&vsh[n][lb];
            u16x4 vb = *(const u16x4*)&vsh[n][lb + 4];
#pragma unroll
            for (int e = 0; e < 4; ++e) acc[e] += kd * bf2f(va[e]);
#pragma unroll
            for (int e = 0; e < 4; ++e) acc[4 + e] += kd * bf2f(vb[e]);
        }
    }
    size_t base = (size_t)(b * 8 + h) * DHc * DHc;
#pragma unroll
    for (int e = 0; e < 8; ++e)
        attn_t[base + (size_t)(lb + e) * DHc + d] = f2bf(acc[e]);
}

// ---------------------------------------------------------------------------
// gemm1: BM=256, BN=128, BK=64, 512 thr (r5-champion).
// A1 @ Wqt + bq -> head-softmax -> q @ attn_t -> out1 bf16
// ---------------------------------------------------------------------------
__global__ void __launch_bounds__(512, 4) gemm1_kernel(
    const unsigned short* __restrict__ A1, const unsigned short* __restrict__ Wt,
    const float* __restrict__ bq, const unsigned short* __restrict__ attn_t,
    unsigned short* __restrict__ out1) {
    __shared__ short lds_s[24576];            // 48 KB: A [0:16384), B [16384:24576)
    short* Alds = lds_s;
    short* Blds = lds_s + 16384;

    const int tid = threadIdx.x, l = tid & 63, w = tid >> 6;
    const int lr = l & 15, lg = l >> 4;
    int raw = blockIdx.x;                      // 1024 blocks, %8==0 -> bijective
    int swz = (raw & 7) * 128 + (raw >> 3);
    int mt = swz >> 2, nt = swz & 3;
    int row0 = mt * 256, col0 = nt * 128;
    int b = row0 >> 13;
    int wrow = (w >> 1) * 64, wcol = (w & 1) * 64;

    f32x4 acc[4][4] = {};

    for (int ks = 0; ks < 8; ++ks) {
#pragma unroll
        for (int i = 0; i < 4; ++i) {          // A: 256 rows x 64 k
            int c = i * 512 + tid;
            int r = c >> 3, kc = c & 7;
            int koff = ks * 64 + ((kc ^ (r & 7)) << 3);
            gload16(A1 + (size_t)(row0 + r) * Dc + koff, &Alds[(i * 8 + w) * 512]);
        }
#pragma unroll
        for (int i = 0; i < 2; ++i) {          // B: 128 rows x 64 k
            int c = i * 512 + tid;
            int r = c >> 3, kc = c & 7;
            int koff = ks * 64 + ((kc ^ (r & 7)) << 3);
            gload16(Wt + (size_t)(col0 + r) * Dc + koff, &Blds[(i * 8 + w) * 512]);
        }
        __syncthreads();
#pragma unroll
        for (int kk = 0; kk < 2; ++kk) {
            int kcw = kk * 4 + lg;
            bf16x8v af[4], bfr[4];
#pragma unroll
            for (int i = 0; i < 4; ++i) {
                int r = wrow + i * 16 + lr;
                af[i] = *(bf16x8v*)&Alds[(r * 8 + (kcw ^ (r & 7))) * 8];
            }
#pragma unroll
            for (int j = 0; j < 4; ++j) {
                int n = wcol + j * 16 + lr;
                bfr[j] = *(bf16x8v*)&Blds[(n * 8 + (kcw ^ (n & 7))) * 8];
            }
#pragma unroll
            for (int i = 0; i < 4; ++i)
#pragma unroll
                for (int j = 0; j < 4; ++j)
                    acc[i][j] = MFMA16(af[i], bfr[j], acc[i][j]);
        }
        __syncthreads();
    }

    float bqv[4];
#pragma unroll
    for (int j = 0; j < 4; ++j) bqv[j] = bq[col0 + wcol + j * 16 + lr];

    // PV B-frags: wave's 64-col block == one head
    int hw = nt * 2 + (wcol >> 6);
    const unsigned short* at = attn_t + (size_t)(b * 8 + hw) * DHc * DHc;
    short* Qw = lds_s + w * 1024;              // per-wave 16x64 scratch in A region

#pragma unroll
    for (int i = 0; i < 4; ++i) {
        // bias + per-(row,head) softmax (16-lane groups)
#pragma unroll
        for (int reg = 0; reg < 4; ++reg) {
            float v0 = acc[i][0][reg] + bqv[0], v1 = acc[i][1][reg] + bqv[1];
            float v2 = acc[i][2][reg] + bqv[2], v3 = acc[i][3][reg] + bqv[3];
            float m = fmaxf(fmaxf(v0, v1), fmaxf(v2, v3));
            m = fmaxf(m, __shfl_xor(m, 1)); m = fmaxf(m, __shfl_xor(m, 2));
            m = fmaxf(m, __shfl_xor(m, 4)); m = fmaxf(m, __shfl_xor(m, 8));
            float e0 = __expf(v0 - m), e1 = __expf(v1 - m);
            float e2 = __expf(v2 - m), e3 = __expf(v3 - m);
            float ssum = e0 + e1 + e2 + e3;
            ssum += __shfl_xor(ssum, 1); ssum += __shfl_xor(ssum, 2);
            ssum += __shfl_xor(ssum, 4); ssum += __shfl_xor(ssum, 8);
            float inv = 1.f / ssum;
            acc[i][0][reg] = e0 * inv; acc[i][1][reg] = e1 * inv;
            acc[i][2][reg] = e2 * inv; acc[i][3][reg] = e3 * inv;
        }
        // q-frag -> per-wave LDS scratch (swizzled), wave-local
#pragma unroll
        for (int j = 0; j < 4; ++j)
#pragma unroll
            for (int reg = 0; reg < 4; ++reg) {
                int rl = 4 * lg + reg;
                int c = j * 16 + lr;
                Qw[(rl * 8 + ((c >> 3) ^ (rl & 7))) * 8 + (c & 7)] =
                    (short)f2bf(acc[i][j][reg]);
            }
        // PV: 16 rows of this frag x attn (64x64)
        f32x4 acc2[4] = {};
#pragma unroll
        for (int kk = 0; kk < 2; ++kk) {
            int kc = kk * 4 + lg;
            bf16x8v a = *(bf16x8v*)&Qw[(lr * 8 + (kc ^ (lr & 7))) * 8];
            bf16x8v bf2[4];
#pragma unroll
            for (int j = 0; j < 4; ++j)
                bf2[j] = *(const bf16x8v*)&at[(j * 16 + lr) * DHc + kk * 32 + lg * 8];
#pragma unroll
            for (int j = 0; j < 4; ++j)
                acc2[j] = MFMA16(a, bf2[j], acc2[j]);
        }
#pragma unroll
        for (int j = 0; j < 4; ++j)
#pragma unroll
            for (int reg = 0; reg < 4; ++reg) {
                int r = row0 + wrow + i * 16 + 4 * lg + reg;
                int c = col0 + wcol + j * 16 + lr;
                out1[(size_t)r * Dc + c] = f2bf(acc2[j][reg]);
            }
    }
}

// ---------------------------------------------------------------------------
// mid: A2 = bf16( silu( LN(out1)*(1+scale)+shift ) )  (r3-proven)
// ---------------------------------------------------------------------------
__global__ void __launch_bounds__(256) mid_kernel(const unsigned short* __restrict__ out1,
                                                  const float* __restrict__ eo,
                                                  const float* __restrict__ g,
                                                  const float* __restrict__ bt,
                                                  unsigned short* __restrict__ A2) {
    int w = threadIdx.x >> 6, l = threadIdx.x & 63;
    int row = blockIdx.x * 4 + w;
    int b = row >> 13;
    u16x8 iv = *(const u16x8*)&out1[(size_t)row * Dc + l * 8];
    float vals[8];
    float s = 0.f, ss = 0.f;
#pragma unroll
    for (int j = 0; j < 8; ++j) {
        vals[j] = bf2f(iv[j]);
        s += vals[j]; ss += vals[j] * vals[j];
    }
#pragma unroll
    for (int m = 1; m <= 32; m <<= 1) { s += __shfl_xor(s, m); ss += __shfl_xor(ss, m); }
    float mean = s * (1.f / Dc), var = ss * (1.f / Dc) - mean * mean;
    float rs = rsqrtf(var + 1e-5f);
    const float* scl = eo + (size_t)b * (2 * Dc);
    const float* shf = scl + Dc;
    u16x8 o;
#pragma unroll
    for (int j = 0; j < 8; ++j) {
        int c = l * 8 + j;
        float t = (vals[j] - mean) * rs * g[c] + bt[c];
        t = t * (1.f + scl[c]) + shf[c];
        t = t / (1.f + __expf(-t));
        o[j] = f2bf(t);
    }
    *(u16x8*)&A2[(size_t)row * Dc + l * 8] = o;
}

// ---------------------------------------------------------------------------
// gemm2: BM=256, BN=128, BK=64, 512 thr (r5-champion, no x-touch).
// out = x + A2 @ oWt + out_b (fp32)
// ---------------------------------------------------------------------------
__global__ void __launch_bounds__(512, 4) gemm2_kernel(
    const unsigned short* __restrict__ A2, const unsigned short* __restrict__ Wt,
    const float* __restrict__ ob, const float* __restrict__ x,
    float* __restrict__ out) {
    __shared__ short lds_s[24576];
    short* Alds = lds_s;
    short* Blds = lds_s + 16384;

    const int tid = threadIdx.x, l = tid & 63, w = tid >> 6;
    const int lr = l & 15, lg = l >> 4;
    int raw = blockIdx.x;
    int swz = (raw & 7) * 128 + (raw >> 3);
    int mt = swz >> 2, nt = swz & 3;
    int row0 = mt * 256, col0 = nt * 128;
    int wrow = (w >> 1) * 64, wcol = (w & 1) * 64;

    f32x4 acc[4][4] = {};

    for (int ks = 0; ks < 8; ++ks) {
#pragma unroll
        for (int i = 0; i < 4; ++i) {
            int c = i * 512 + tid;
            int r = c >> 3, kc = c & 7;
            int koff = ks * 64 + ((kc ^ (r & 7)) << 3);
            gload16(A2 + (size_t)(row0 + r) * Dc + koff, &Alds[(i * 8 + w) * 512]);
        }
#pragma unroll
        for (int i = 0; i < 2; ++i) {
            int c = i * 512 + tid;
            int r = c >> 3, kc = c & 7;
            int koff = ks * 64 + ((kc ^ (r & 7)) << 3);
            gload16(Wt + (size_t)(col0 + r) * Dc + koff, &Blds[(i * 8 + w) * 512]);
        }
        __syncthreads();
#pragma unroll
        for (int kk = 0; kk < 2; ++kk) {
            int kcw = kk * 4 + lg;
            bf16x8v af[4], bfr[4];
#pragma unroll
            for (int i = 0; i < 4; ++i) {
                int r = wrow + i * 16 + lr;
                af[i] = *(bf16x8v*)&Alds[(r * 8 + (kcw ^ (r & 7))) * 8];
            }
#pragma unroll
            for (int j = 0; j < 4; ++j) {
                int n = wcol + j * 16 + lr;
                bfr[j] = *(bf16x8v*)&Blds[(n * 8 + (kcw ^ (n & 7))) * 8];
            }
#pragma unroll
            for (int i = 0; i < 4; ++i)
#pragma unroll
                for (int j = 0; j < 4; ++j)
                    acc[i][j] = MFMA16(af[i], bfr[j], acc[i][j]);
        }
        __syncthreads();
    }

    float obv[4];
#pragma unroll
    for (int j = 0; j < 4; ++j) obv[j] = ob[col0 + wcol + j * 16 + lr];
#pragma unroll
    for (int i = 0; i < 4; ++i)
#pragma unroll
        for (int j = 0; j < 4; ++j)
#pragma unroll
            for (int reg = 0; reg < 4; ++reg) {
                int r = row0 + wrow + i * 16 + 4 * lg + reg;
                int c = col0 + wcol + j * 16 + lr;
                size_t o = (size_t)r * Dc + c;
                out[o] = acc[i][j][reg] + obv[j] + x[o];
            }
}

// ---------------------------------------------------------------------------
extern "C" void kernel_launch(void* const* d_in, const int* in_sizes, int n_in,
                              void* d_out, int out_size, void* d_ws, size_t ws_size,
                              hipStream_t stream) {
    const float* x      = (const float*)d_in[0];
    const float* xf     = (const float*)d_in[1];
    const float* emb    = (const float*)d_in[2];
    const float* ln_x_g = (const float*)d_in[3];
    const float* ln_x_b = (const float*)d_in[4];
    const float* ln_t_g = (const float*)d_in[5];
    const float* ln_t_b = (const float*)d_in[6];
    const float* Wq     = (const float*)d_in[7];
    const float* bq     = (const float*)d_in[8];
    const float* Wk     = (const float*)d_in[9];
    const float* bk     = (const float*)d_in[10];
    const float* Wv     = (const float*)d_in[11];
    const float* bv     = (const float*)d_in[12];
    const float* emb_W  = (const float*)d_in[13];
    const float* emb_b  = (const float*)d_in[14];
    const float* ln_o_g = (const float*)d_in[15];
    const float* ln_o_b = (const float*)d_in[16];
    const float* out_W  = (const float*)d_in[17];
    const float* out_b  = (const float*)d_in[18];
    float* out = (float*)d_out;

    // ws layout (u16 units unless noted)
    unsigned short* xt   = (unsigned short*)d_ws;                 // 2048*768
    unsigned short* kbuf = xt + (size_t)2048 * TXT;               // 2048*512
    unsigned short* vbuf = kbuf + (size_t)2048 * 512;             // 2048*512
    unsigned short* Wkvt = vbuf + (size_t)2048 * 512;             // 1024*768
    unsigned short* Wqt  = Wkvt + (size_t)1024 * TXT;             // 512*512
    unsigned short* oWt  = Wqt + (size_t)512 * 512;               // 512*512
    unsigned short* attn_t = oWt + (size_t)512 * 512;             // 64*64*64
    float* eo = (float*)(attn_t + (size_t)64 * 64 * 64);          // 8*1024 f32
    unsigned short* out1 = (unsigned short*)(eo + 8 * 1024);      // 65536*512
    unsigned short* A1   = out1 + (size_t)MROWS * Dc;             // 65536*512
    unsigned short* A2   = A1;                                    // overlay (A1 dead)

    hipLaunchKernelGGL(prep_kernel, dim3(832), dim3(256), 0, stream,
                       Wq, out_W, Wk, Wv, xf, ln_t_g, ln_t_b, Wqt, oWt, Wkvt, xt);
    hipLaunchKernelGGL(ln_x_kernel, dim3(MROWS / 4), dim3(256), 0, stream,
                       x, ln_x_g, ln_x_b, A1);
    hipLaunchKernelGGL(kvgemm_kernel, dim3(16 * 8), dim3(256), 0, stream,
                       xt, Wkvt, bk, bv, kbuf, vbuf);
    hipLaunchKernelGGL(attn_kernel, dim3(Bc * Hc), dim3(512), 0, stream,
                       kbuf, vbuf, attn_t);
    hipLaunchKernelGGL(emb_kernel, dim3(Bc * 16), dim3(256), 0, stream,
                       emb, emb_W, emb_b, eo);
    hipLaunchKernelGGL(gemm1_kernel, dim3(MROWS / 256 * 4), dim3(512), 0, stream,
                       A1, Wqt, bq, attn_t, out1);
    hipLaunchKernelGGL(mid_kernel, dim3(MROWS / 4), dim3(256), 0, stream,
                       out1, eo, ln_o_g, ln_o_b, A2);
    hipLaunchKernelGGL(gemm2_kernel, dim3(MROWS / 256 * 4), dim3(512), 0, stream,
                       A2, oWt, out_b, x, out);
}